// Round 1
// baseline (5075.369 us; speedup 1.0000x reference)
//
#include <hip/hip_runtime.h>
#include <hip/hip_bf16.h>
#include <stdint.h>

#define TT 1024
#define BBATCH 256
#define DD 256
#define HH 256
#define G4 1024   // 4*H

typedef float f32x4 __attribute__((ext_vector_type(4)));
typedef short bf16x8 __attribute__((ext_vector_type(8)));
typedef int   i32x4  __attribute__((ext_vector_type(4)));

__device__ __forceinline__ float bf2f(unsigned int u) {
  union { unsigned int i; float f; } v; v.i = u << 16; return v.f;
}
__device__ __forceinline__ unsigned short f2bf(float f) {
  union { float f; unsigned int i; } v; v.f = f;
  unsigned int r = v.i + 0x7FFFu + ((v.i >> 16) & 1u);
  return (unsigned short)(r >> 16);
}
__device__ __forceinline__ float sigm(float x) { return 1.f / (1.f + __expf(-x)); }
__device__ __forceinline__ float tanhfast(float x) { float e = __expf(2.f * x); return 1.f - 2.f / (e + 1.f); }

// ---------------- prep kernels ----------------

// W_ih fp32 [1024][256] -> bf16 same layout
__global__ void prep_wih(const float* __restrict__ wih, unsigned short* __restrict__ out) {
  int i = blockIdx.x * 1024 + threadIdx.x * 4;
#pragma unroll
  for (int j = 0; j < 4; ++j) out[i + j] = f2bf(wih[i + j]);
}

// W_y fp32 [256 k][256 d] -> bf16 transposed wyt[d][k]
__global__ void prep_wyt(const float* __restrict__ wy, unsigned short* __restrict__ wyt) {
  int k = blockIdx.x;   // 0..255
  int d = threadIdx.x;  // 0..255
  wyt[d * 256 + k] = f2bf(wy[k * 256 + d]);
}

// W_hh fp32 [1024 g][256 k] -> per-row-scaled int8 packed in MFMA B-frag order,
// plus dequant scales dsc[g] = rowmax/127^2, plus hh0[g] = sum_k W_hh[g,k]*h0[k] (exact fp32).
// Pack position for (g,k): g = sec*256 + w*32 + m*16 + cl ; nt = sec*2+m
//   kt=k>>6, hi=(k>>4)&3, j=k&15, lane = cl|(hi<<4)
//   byte = (((w*8+nt)*4+kt)*64 + lane)*16 + j
__global__ void prep_whh(const float* __restrict__ whh, const float* __restrict__ h0,
                         signed char* __restrict__ wq, float* __restrict__ dsc,
                         float* __restrict__ hh0) {
  int g = blockIdx.x;       // 0..1023
  int lane = threadIdx.x;   // 0..63
  float v[4];
  float mx = 0.f, acc = 0.f;
#pragma unroll
  for (int j = 0; j < 4; ++j) {
    v[j] = whh[g * 256 + lane * 4 + j];
    mx = fmaxf(mx, fabsf(v[j]));
    acc += v[j] * h0[lane * 4 + j];
  }
#pragma unroll
  for (int off = 32; off; off >>= 1) {
    mx  = fmaxf(mx, __shfl_xor(mx, off));
    acc = acc + __shfl_xor(acc, off);
  }
  mx = fmaxf(mx, 1e-12f);
  if (lane == 0) { dsc[g] = mx / (127.f * 127.f); hh0[g] = acc; }
  int sec = g >> 8, w = (g >> 5) & 7, m = (g >> 4) & 1, cl = g & 15;
  int nt = sec * 2 + m;
  float inv = 127.f / mx;
  int k0 = lane * 4;
  int kt = k0 >> 6, hi = (k0 >> 4) & 3, jj = k0 & 15;
  int base = ((((w * 8 + nt) * 4 + kt) * 64) + (cl | (hi << 4))) * 16 + jj;
#pragma unroll
  for (int j = 0; j < 4; ++j) {
    int q = (int)rintf(v[j] * inv);
    q = q > 127 ? 127 : (q < -127 ? -127 : q);
    wq[base + j] = (signed char)q;
  }
}

// ---------------- phase 1: xw[t][b][g] = x[b,t,:] @ W_ih^T + b_ih, bf16 ----------------
// grid (8, 4096), block 256. M-tile = 64 rows of one batch b (t-chunk of 64), N-tile 128.
__global__ __launch_bounds__(256, 4) void xw_gemm(const float* __restrict__ x,
                                                  const unsigned short* __restrict__ wb,
                                                  const float* __restrict__ bih,
                                                  unsigned short* __restrict__ xw) {
  __shared__ __align__(16) unsigned short xa[64 * 256];  // 32KB, XOR-swizzled
  int tid = threadIdx.x;
  int gblk = blockIdx.x;            // 0..7
  int mt = blockIdx.y;              // 0..4095
  int bb = mt >> 4;
  int t0 = (mt & 15) * 64;
  {
    int row = tid >> 2, q = tid & 3;
    const float* src = x + ((size_t)bb * TT + (t0 + row)) * DD;
#pragma unroll
    for (int i = 0; i < 16; ++i) {
      int c4 = q + i * 4;  // float4 index 0..63
      float4 vv = *(const float4*)(src + c4 * 4);
      unsigned long long pk = (unsigned long long)f2bf(vv.x)
                            | ((unsigned long long)f2bf(vv.y) << 16)
                            | ((unsigned long long)f2bf(vv.z) << 32)
                            | ((unsigned long long)f2bf(vv.w) << 48);
      *(unsigned long long*)((char*)xa + row * 512 + ((c4 * 8) ^ ((row & 7) << 4))) = pk;
    }
  }
  __syncthreads();
  int lane = tid & 63, wv = tid >> 6;
  int wr = wv >> 1, wc = wv & 1;
  int lr = lane & 15, hi = lane >> 4;
  f32x4 acc[2][4];
#pragma unroll
  for (int a = 0; a < 2; ++a)
#pragma unroll
    for (int b = 0; b < 4; ++b) acc[a][b] = (f32x4){0.f, 0.f, 0.f, 0.f};
  int gbase = gblk * 128 + wc * 64;
  float bias[4];
#pragma unroll
  for (int nt = 0; nt < 4; ++nt) bias[nt] = bih[gbase + nt * 16 + lr];
#pragma unroll
  for (int k0 = 0; k0 < 8; ++k0) {
    bf16x8 a[2], b[4];
#pragma unroll
    for (int mti = 0; mti < 2; ++mti) {
      int row = wr * 32 + mti * 16 + lr;
      a[mti] = *(const bf16x8*)((const char*)xa + row * 512 + ((k0 * 64 + hi * 16) ^ ((row & 7) << 4)));
    }
#pragma unroll
    for (int nt = 0; nt < 4; ++nt) {
      b[nt] = *(const bf16x8*)(wb + (size_t)(gbase + nt * 16 + lr) * 256 + k0 * 32 + hi * 8);
#pragma unroll
      for (int mti = 0; mti < 2; ++mti)
        acc[mti][nt] = __builtin_amdgcn_mfma_f32_16x16x32_bf16(a[mti], b[nt], acc[mti][nt], 0, 0, 0);
    }
  }
#pragma unroll
  for (int mti = 0; mti < 2; ++mti)
#pragma unroll
    for (int nt = 0; nt < 4; ++nt) {
      int g = gbase + nt * 16 + lr;
#pragma unroll
      for (int r = 0; r < 4; ++r) {
        int trow = t0 + wr * 32 + mti * 16 + hi * 4 + r;
        xw[((size_t)trow * BBATCH + bb) * G4 + g] = f2bf(acc[mti][nt][r] + bias[nt]);
      }
    }
}

// ---------------- phase 2: the scan ----------------
// 64 blocks x 512 threads (8 waves). Each block owns 4 batch rows; W_hh int8 lives in VGPRs.
// hs (bf16) is overlaid into the first 512B of each already-consumed xw[t][b] slab row.
__global__ __launch_bounds__(512, 2) void lstm_scan(unsigned short* xw,
                                                    const signed char* __restrict__ wq,
                                                    const float* __restrict__ dsc,
                                                    const float* __restrict__ hh0,
                                                    const float* __restrict__ c0,
                                                    float* __restrict__ out) {
  __shared__ __align__(16) signed char hq[2][4][64][16];       // 8KB: int8 h A-frags, dbuf
  __shared__ __align__(8) unsigned short xwb[2][1024][4];      // 16KB: xw staged [g][b], dbuf
  int tid = threadIdx.x;
  int lane = tid & 63, wv = tid >> 6;
  int lr = lane & 15;
  int b0 = blockIdx.x * 4;

  // resident W frags: [nt][kt], 128 VGPRs of int8
  i32x4 wf[8][4];
  {
    const i32x4* wp = (const i32x4*)(wq + (size_t)wv * 8 * 4 * 64 * 16);
#pragma unroll
    for (int nt = 0; nt < 8; ++nt)
#pragma unroll
      for (int kt = 0; kt < 4; ++kt) wf[nt][kt] = wp[(nt * 4 + kt) * 64 + lane];
  }
  float dr[4][2], h0r[4][2];
#pragma unroll
  for (int sec = 0; sec < 4; ++sec)
#pragma unroll
    for (int m = 0; m < 2; ++m) {
      int g = sec * 256 + wv * 32 + m * 16 + lr;
      dr[sec][m] = dsc[g];
      h0r[sec][m] = hh0[g];
    }
  float cr[2][4];
#pragma unroll
  for (int m = 0; m < 2; ++m) {
    float cv = c0[wv * 32 + m * 16 + lr];
#pragma unroll
    for (int b = 0; b < 4; ++b) cr[m][b] = cv;
  }
  // zero both hq buffers (t=0 uses hh0 added exactly in fp32 instead of quantized h0)
  {
    i32x4 z = {0, 0, 0, 0};
    *(i32x4*)((char*)&hq[0][0][0][0] + tid * 16) = z;  // 512*16 = 8KB total
  }
  // prologue: stage xw[0]
  {
    int sb = tid >> 7, sg = (tid & 127) * 8;
    int4 xin = *(const int4*)(xw + ((size_t)0 * BBATCH + b0 + sb) * G4 + sg);
    unsigned short* vs = (unsigned short*)&xin;
#pragma unroll
    for (int i = 0; i < 8; ++i) xwb[0][sg + i][sb] = vs[i];
  }
  __syncthreads();

  const size_t ybytes = (size_t)BBATCH * TT * DD;
  int cur = 0;
  for (int t = 0; t < TT; ++t) {
    int nxt = cur ^ 1;
    // issue next-step xw staging load (consumed after this step's compute)
    int tn = (t + 1 < TT) ? t + 1 : TT - 1;
    int sb = tid >> 7, sg = (tid & 127) * 8;
    int4 xin = *(const int4*)(xw + ((size_t)tn * BBATCH + b0 + sb) * G4 + sg);

    // pre-GEMM: [16(4 used) x 256] @ [256 x 128 cols/wave] in int8
    i32x4 acc[8];
    {
      i32x4 z = {0, 0, 0, 0};
#pragma unroll
      for (int nt = 0; nt < 8; ++nt) acc[nt] = z;
    }
#pragma unroll
    for (int kt = 0; kt < 4; ++kt) {
      i32x4 af = *(const i32x4*)&hq[cur][kt][lane][0];
#pragma unroll
      for (int nt = 0; nt < 8; ++nt)
        acc[nt] = __builtin_amdgcn_mfma_i32_16x16x64_i8(af, wf[nt][kt], acc[nt], 0, 0, 0);
    }
    // gate update (lanes 0..15 hold batch rows 0..3 in acc regs)
    if (lane < 16) {
#pragma unroll
      for (int m = 0; m < 2; ++m) {
        int kg = wv * 32 + m * 16 + lr;
        float xf[4][4];
#pragma unroll
        for (int sec = 0; sec < 4; ++sec) {
          const unsigned int* p = (const unsigned int*)&xwb[cur][sec * 256 + kg][0];
          unsigned int u0 = p[0], u1 = p[1];
          xf[sec][0] = bf2f(u0 & 0xffffu); xf[sec][1] = bf2f(u0 >> 16);
          xf[sec][2] = bf2f(u1 & 0xffffu); xf[sec][3] = bf2f(u1 >> 16);
        }
        int hi2 = ((wv & 1) << 1) | m;
#pragma unroll
        for (int b = 0; b < 4; ++b) {
          float gi = fmaf(dr[0][m], (float)acc[0 + m][b], xf[0][b]);
          float gf = fmaf(dr[1][m], (float)acc[2 + m][b], xf[1][b]);
          float gj = fmaf(dr[2][m], (float)acc[4 + m][b], xf[2][b]);
          float go = fmaf(dr[3][m], (float)acc[6 + m][b], xf[3][b]);
          if (t == 0) { gi += h0r[0][m]; gf += h0r[1][m]; gj += h0r[2][m]; go += h0r[3][m]; }
          float iv = sigm(gi), fv = sigm(gf), jv = tanhfast(gj), ov = sigm(go);
          float cn = fv * cr[m][b] + iv * jv;
          cr[m][b] = cn;
          float hn = ov * tanhfast(cn);
          // int8 h frag for next step (|hn|<1 so scale 127 is exact-range)
          hq[nxt][wv >> 1][b | (hi2 << 4)][lr] = (signed char)(int)rintf(hn * 127.f);
          // hs (bf16) overlaid into consumed xw[t][b] slab head
          xw[(size_t)t * (BBATCH * G4) + (size_t)(b0 + b) * G4 + kg] = f2bf(hn);
          if (t == TT - 1) {
            out[ybytes + (size_t)(b0 + b) * HH + kg] = hn;
            out[ybytes + (size_t)BBATCH * HH + (size_t)(b0 + b) * HH + kg] = cn;
          }
        }
      }
    }
    // write staged xw into LDS (transposed to [g][b])
    {
      unsigned short* vs = (unsigned short*)&xin;
#pragma unroll
      for (int i = 0; i < 8; ++i) xwb[nxt][sg + i][sb] = vs[i];
    }
    __syncthreads();
    cur = nxt;
  }
}

// ---------------- phase 3: y = hs @ W_y + b_y ----------------
// hs lives at xw base with layout: elem index t*262144 + b*1024 + k (k<256). grid (2,4096), block 256.
__global__ __launch_bounds__(256, 4) void y_gemm(const unsigned short* __restrict__ hsx,
                                                 const unsigned short* __restrict__ wyt,
                                                 const float* __restrict__ by,
                                                 float* __restrict__ y) {
  __shared__ __align__(16) unsigned short ha[64 * 256];  // 32KB
  int tid = threadIdx.x;
  int dblk = blockIdx.x;  // 0..1
  int mt = blockIdx.y;    // 0..4095
  int bb = mt >> 4;
  int t0 = (mt & 15) * 64;
  {
    int row = tid >> 2, q = tid & 3;
    const unsigned short* src = hsx + (size_t)(t0 + row) * (BBATCH * G4) / 1 * 0 + 0;  // placeholder
    src = hsx + (size_t)(t0 + row) * (size_t)(BBATCH * 1024) + (size_t)bb * 1024;
#pragma unroll
    for (int i = 0; i < 8; ++i) {
      int u = q + i * 4;  // 16B unit, 0..31
      int4 vv = *(const int4*)(src + u * 8);
      *(int4*)((char*)ha + row * 512 + ((u * 16) ^ ((row & 7) << 4))) = vv;
    }
  }
  __syncthreads();
  int lane = tid & 63, wv = tid >> 6;
  int wr = wv >> 1, wc = wv & 1;
  int lr = lane & 15, hi = lane >> 4;
  f32x4 acc[2][4];
#pragma unroll
  for (int a = 0; a < 2; ++a)
#pragma unroll
    for (int b = 0; b < 4; ++b) acc[a][b] = (f32x4){0.f, 0.f, 0.f, 0.f};
  int dbase = dblk * 128 + wc * 64;
#pragma unroll
  for (int k0 = 0; k0 < 8; ++k0) {
    bf16x8 a[2], b[4];
#pragma unroll
    for (int mti = 0; mti < 2; ++mti) {
      int row = wr * 32 + mti * 16 + lr;
      a[mti] = *(const bf16x8*)((const char*)ha + row * 512 + ((k0 * 64 + hi * 16) ^ ((row & 7) << 4)));
    }
#pragma unroll
    for (int nt = 0; nt < 4; ++nt) {
      b[nt] = *(const bf16x8*)(wyt + (size_t)(dbase + nt * 16 + lr) * 256 + k0 * 32 + hi * 8);
#pragma unroll
      for (int mti = 0; mti < 2; ++mti)
        acc[mti][nt] = __builtin_amdgcn_mfma_f32_16x16x32_bf16(a[mti], b[nt], acc[mti][nt], 0, 0, 0);
    }
  }
#pragma unroll
  for (int mti = 0; mti < 2; ++mti)
#pragma unroll
    for (int nt = 0; nt < 4; ++nt) {
      int d = dbase + nt * 16 + lr;
      float bv = by[d];
#pragma unroll
      for (int r = 0; r < 4; ++r) {
        int trow = t0 + wr * 32 + mti * 16 + hi * 4 + r;
        y[((size_t)bb * TT + trow) * DD + d] = acc[mti][nt][r] + bv;
      }
    }
}

// ---------------- launch ----------------
extern "C" void kernel_launch(void* const* d_in, const int* in_sizes, int n_in,
                              void* d_out, int out_size, void* d_ws, size_t ws_size,
                              hipStream_t stream) {
  const float* x   = (const float*)d_in[0];
  const float* wih = (const float*)d_in[1];
  const float* bih = (const float*)d_in[2];
  const float* whh = (const float*)d_in[3];
  const float* h0  = (const float*)d_in[4];
  const float* c0  = (const float*)d_in[5];
  const float* wy  = (const float*)d_in[6];
  const float* by  = (const float*)d_in[7];
  float* out = (float*)d_out;
  char* ws = (char*)d_ws;

  size_t off = 0;
  unsigned short* xw = (unsigned short*)(ws + off); off += (size_t)TT * BBATCH * G4 * 2;  // 512MB
  unsigned short* wbf = (unsigned short*)(ws + off); off += (size_t)G4 * DD * 2;          // 512KB
  unsigned short* wyt = (unsigned short*)(ws + off); off += (size_t)HH * DD * 2;          // 128KB
  signed char* wq = (signed char*)(ws + off); off += (size_t)G4 * HH;                     // 256KB
  float* dsc = (float*)(ws + off); off += G4 * 4;
  float* hh0 = (float*)(ws + off); off += G4 * 4;

  hipLaunchKernelGGL(prep_wih, dim3(256), dim3(256), 0, stream, wih, wbf);
  hipLaunchKernelGGL(prep_wyt, dim3(256), dim3(256), 0, stream, wy, wyt);
  hipLaunchKernelGGL(prep_whh, dim3(1024), dim3(64), 0, stream, whh, h0, wq, dsc, hh0);
  hipLaunchKernelGGL(xw_gemm, dim3(8, 4096), dim3(256), 0, stream, x, wbf, bih, xw);
  hipLaunchKernelGGL(lstm_scan, dim3(64), dim3(512), 0, stream, xw, wq, dsc, hh0, c0, out);
  hipLaunchKernelGGL(y_gemm, dim3(2, 4096), dim3(256), 0, stream, xw, wyt, by, out);
}

// Round 2
// 1918.071 us; speedup vs baseline: 2.6461x; 2.6461x over previous
//
#include <hip/hip_runtime.h>
#include <hip/hip_bf16.h>
#include <stdint.h>

#define TT 1024
#define BBATCH 256
#define DD 256
#define HH 256
#define G4 1024   // 4*H

typedef float f32x4 __attribute__((ext_vector_type(4)));
typedef short bf16x8 __attribute__((ext_vector_type(8)));
typedef int   i32x4  __attribute__((ext_vector_type(4)));

__device__ __forceinline__ float bf2f(unsigned int u) {
  union { unsigned int i; float f; } v; v.i = u << 16; return v.f;
}
__device__ __forceinline__ unsigned short f2bf(float f) {
  union { float f; unsigned int i; } v; v.f = f;
  unsigned int r = v.i + 0x7FFFu + ((v.i >> 16) & 1u);
  return (unsigned short)(r >> 16);
}
__device__ __forceinline__ float sigm(float x) { return 1.f / (1.f + __expf(-x)); }
__device__ __forceinline__ float tanhfast(float x) { float e = __expf(2.f * x); return 1.f - 2.f / (e + 1.f); }

// ---------------- prep kernels ----------------

__global__ void prep_wih(const float* __restrict__ wih, unsigned short* __restrict__ out) {
  int i = blockIdx.x * 1024 + threadIdx.x * 4;
#pragma unroll
  for (int j = 0; j < 4; ++j) out[i + j] = f2bf(wih[i + j]);
}

__global__ void prep_wyt(const float* __restrict__ wy, unsigned short* __restrict__ wyt) {
  int k = blockIdx.x;
  int d = threadIdx.x;
  wyt[d * 256 + k] = f2bf(wy[k * 256 + d]);
}

// W_hh fp32 [1024 g][256 k] -> per-row-scaled int8 packed in MFMA B-frag order,
// dsc[g] = rowmax/127^2, hh0[g] = W_hh[g,:]·h0 (exact fp32).
__global__ void prep_whh(const float* __restrict__ whh, const float* __restrict__ h0,
                         signed char* __restrict__ wq, float* __restrict__ dsc,
                         float* __restrict__ hh0) {
  int g = blockIdx.x;
  int lane = threadIdx.x;
  float v[4];
  float mx = 0.f, acc = 0.f;
#pragma unroll
  for (int j = 0; j < 4; ++j) {
    v[j] = whh[g * 256 + lane * 4 + j];
    mx = fmaxf(mx, fabsf(v[j]));
    acc += v[j] * h0[lane * 4 + j];
  }
#pragma unroll
  for (int off = 32; off; off >>= 1) {
    mx  = fmaxf(mx, __shfl_xor(mx, off));
    acc = acc + __shfl_xor(acc, off);
  }
  mx = fmaxf(mx, 1e-12f);
  if (lane == 0) { dsc[g] = mx / (127.f * 127.f); hh0[g] = acc; }
  int sec = g >> 8, w = (g >> 5) & 7, m = (g >> 4) & 1, cl = g & 15;
  int nt = sec * 2 + m;
  float inv = 127.f / mx;
  int k0 = lane * 4;
  int kt = k0 >> 6, hi = (k0 >> 4) & 3, jj = k0 & 15;
  int base = ((((w * 8 + nt) * 4 + kt) * 64) + (cl | (hi << 4))) * 16 + jj;
#pragma unroll
  for (int j = 0; j < 4; ++j) {
    int q = (int)rintf(v[j] * inv);
    q = q > 127 ? 127 : (q < -127 ? -127 : q);
    wq[base + j] = (signed char)q;
  }
}

// xw[0][b][g] += hh0[g]  (folds the h0@W_hh^T contribution into step 0's xw)
__global__ void fix_xw0(unsigned short* __restrict__ xw, const float* __restrict__ hh0) {
  int i = blockIdx.x * 256 + threadIdx.x;   // grid 1024 -> 262144 elems
  int g = i & (G4 - 1);
  xw[i] = f2bf(bf2f(xw[i]) + hh0[g]);
}

// ---------------- phase 1: xw[t][b][g] = x[b,t,:] @ W_ih^T + b_ih, bf16 ----------------
// grid 4096, block 256. Each block: stage one 64x256 x-tile, loop all 8 g-blocks (reuse tile).
__global__ __launch_bounds__(256, 4) void xw_gemm(const float* __restrict__ x,
                                                  const unsigned short* __restrict__ wb,
                                                  const float* __restrict__ bih,
                                                  unsigned short* __restrict__ xw) {
  __shared__ __align__(16) unsigned short xa[64 * 256];  // 32KB, XOR-swizzled
  int tid = threadIdx.x;
  int mt = blockIdx.x;
  int bb = mt >> 4;
  int t0 = (mt & 15) * 64;
  {
    int row = tid >> 2, q = tid & 3;
    const float* src = x + ((size_t)bb * TT + (t0 + row)) * DD;
#pragma unroll
    for (int i = 0; i < 16; ++i) {
      int c4 = q + i * 4;
      float4 vv = *(const float4*)(src + c4 * 4);
      unsigned long long pk = (unsigned long long)f2bf(vv.x)
                            | ((unsigned long long)f2bf(vv.y) << 16)
                            | ((unsigned long long)f2bf(vv.z) << 32)
                            | ((unsigned long long)f2bf(vv.w) << 48);
      *(unsigned long long*)((char*)xa + row * 512 + ((c4 * 8) ^ ((row & 7) << 4))) = pk;
    }
  }
  __syncthreads();
  int lane = tid & 63, wv = tid >> 6;
  int wr = wv >> 1, wc = wv & 1;
  int lr = lane & 15, hi = lane >> 4;
#pragma unroll 1
  for (int gblk = 0; gblk < 8; ++gblk) {
    f32x4 acc[2][4];
#pragma unroll
    for (int a = 0; a < 2; ++a)
#pragma unroll
      for (int b = 0; b < 4; ++b) acc[a][b] = (f32x4){0.f, 0.f, 0.f, 0.f};
    int gbase = gblk * 128 + wc * 64;
    float bias[4];
#pragma unroll
    for (int nt = 0; nt < 4; ++nt) bias[nt] = bih[gbase + nt * 16 + lr];
#pragma unroll
    for (int k0 = 0; k0 < 8; ++k0) {
      bf16x8 a[2], b[4];
#pragma unroll
      for (int mti = 0; mti < 2; ++mti) {
        int row = wr * 32 + mti * 16 + lr;
        a[mti] = *(const bf16x8*)((const char*)xa + row * 512 + ((k0 * 64 + hi * 16) ^ ((row & 7) << 4)));
      }
#pragma unroll
      for (int nt = 0; nt < 4; ++nt) {
        b[nt] = *(const bf16x8*)(wb + (size_t)(gbase + nt * 16 + lr) * 256 + k0 * 32 + hi * 8);
#pragma unroll
        for (int mti = 0; mti < 2; ++mti)
          acc[mti][nt] = __builtin_amdgcn_mfma_f32_16x16x32_bf16(a[mti], b[nt], acc[mti][nt], 0, 0, 0);
      }
    }
#pragma unroll
    for (int mti = 0; mti < 2; ++mti)
#pragma unroll
      for (int nt = 0; nt < 4; ++nt) {
        int g = gbase + nt * 16 + lr;
#pragma unroll
        for (int r = 0; r < 4; ++r) {
          int trow = t0 + wr * 32 + mti * 16 + hi * 4 + r;
          xw[((size_t)trow * BBATCH + bb) * G4 + g] = f2bf(acc[mti][nt][r] + bias[nt]);
        }
      }
  }
}

// ---------------- phase 2: the scan ----------------
// 64 blocks x 512 threads. Block owns 4 batches; batch b sits in A/C row 4b so after MFMA
// every lane holds (batch = lane>>4, g-col = lane&15): all 64 lanes do gate math (2 sets each).
// xw values loaded per-lane directly from global (prefetched 1 step ahead); no LDS xw staging.
__global__ __launch_bounds__(512, 2) void lstm_scan(unsigned short* xw,
                                                    const signed char* __restrict__ wq,
                                                    const float* __restrict__ dsc,
                                                    const float* __restrict__ c0,
                                                    float* __restrict__ out) {
  __shared__ __align__(16) signed char hq[2][4][64][16];  // 8KB, double-buffered int8 h A-frags
  int tid = threadIdx.x;
  int lane = tid & 63, wv = tid >> 6;
  int lr = lane & 15, q = lane >> 4;
  int b0 = blockIdx.x * 4;
  signed char* hqb = (signed char*)hq;

  // resident W_hh int8 B-frags: 128 VGPRs
  i32x4 wf[8][4];
  {
    const i32x4* wp = (const i32x4*)(wq + (size_t)wv * (8 * 4 * 64 * 16));
#pragma unroll
    for (int nt = 0; nt < 8; ++nt)
#pragma unroll
      for (int kt = 0; kt < 4; ++kt) wf[nt][kt] = wp[(nt * 4 + kt) * 64 + lane];
  }
  float dr[4][2];
#pragma unroll
  for (int sec = 0; sec < 4; ++sec)
#pragma unroll
    for (int m = 0; m < 2; ++m) dr[sec][m] = dsc[sec * 256 + wv * 32 + m * 16 + lr];
  float cr[2], lh[2];
  cr[0] = c0[wv * 32 + lr];
  cr[1] = c0[wv * 32 + 16 + lr];
  lh[0] = lh[1] = 0.f;

  // zero both hq buffers (8KB = 512 threads * 16B)
  *(i32x4*)(hqb + tid * 16) = (i32x4){0, 0, 0, 0};

  // per-lane global pointers into xw[t][b0+q][...]
  unsigned short* ldb = xw + (size_t)(b0 + q) * G4 + wv * 32 + lr;  // load base (row t)
  unsigned int xrA[8], xrB[8];
#pragma unroll
  for (int sec = 0; sec < 4; ++sec)
#pragma unroll
    for (int m = 0; m < 2; ++m) xrA[sec * 2 + m] = ldb[sec * 256 + m * 16];
  unsigned short* stb = ldb;            // hs store base (row t)
  ldb += (size_t)BBATCH * G4;           // now row t+1

  const int hqr = lane * 16;                                            // A-frag read offset
  const int hqw = (wv >> 1) * 1024 + (wv & 1) * 512 + q * 64 + lr;      // h write offset
  const i32x4 zero4 = {0, 0, 0, 0};

  __syncthreads();  // hq zero visible

#define STEP(XC, XN, RB) { \
    i32x4 acc[8]; \
    _Pragma("unroll") \
    for (int kt = 0; kt < 4; ++kt) { \
      i32x4 af = *(const i32x4*)(hqb + (RB) + hqr + kt * 1024); \
      _Pragma("unroll") \
      for (int nt = 0; nt < 8; ++nt) \
        acc[nt] = __builtin_amdgcn_mfma_i32_16x16x64_i8(af, wf[nt][kt], kt == 0 ? zero4 : acc[nt], 0, 0, 0); \
    } \
    _Pragma("unroll") \
    for (int sec = 0; sec < 4; ++sec) \
      _Pragma("unroll") \
      for (int m = 0; m < 2; ++m) XN[sec * 2 + m] = ldb[sec * 256 + m * 16]; \
    ldb += (size_t)BBATCH * G4; \
    _Pragma("unroll") \
    for (int m = 0; m < 2; ++m) { \
      float gi = fmaf(dr[0][m], (float)acc[0 + m][0], bf2f(XC[0 + m])); \
      float gf = fmaf(dr[1][m], (float)acc[2 + m][0], bf2f(XC[2 + m])); \
      float gj = fmaf(dr[2][m], (float)acc[4 + m][0], bf2f(XC[4 + m])); \
      float go = fmaf(dr[3][m], (float)acc[6 + m][0], bf2f(XC[6 + m])); \
      float iv = sigm(gi), fv = sigm(gf), jv = tanhfast(gj), ov = sigm(go); \
      float cn = fmaf(fv, cr[m], iv * jv); \
      cr[m] = cn; \
      float hn = ov * tanhfast(cn); \
      lh[m] = hn; \
      hqb[((RB) ^ 4096) + hqw + m * 256] = (signed char)(int)rintf(hn * 127.f); \
      stb[m * 16] = f2bf(hn); \
    } \
    stb += (size_t)BBATCH * G4; \
    asm volatile("s_waitcnt lgkmcnt(0)" ::: "memory"); \
    __builtin_amdgcn_s_barrier(); \
  }

#pragma unroll 1
  for (int t = 0; t < TT; t += 2) {
    STEP(xrA, xrB, 0)
    STEP(xrB, xrA, 4096)
  }
#undef STEP

  const size_t youts = (size_t)BBATCH * TT * DD;
#pragma unroll
  for (int m = 0; m < 2; ++m) {
    int kg = wv * 32 + m * 16 + lr;
    out[youts + (size_t)(b0 + q) * HH + kg] = lh[m];
    out[youts + (size_t)BBATCH * HH + (size_t)(b0 + q) * HH + kg] = cr[m];
  }
}

// ---------------- phase 3: y = hs @ W_y + b_y ----------------
// grid 4096, block 256; stage one 64x256 hs tile, loop both 128-col d-blocks.
__global__ __launch_bounds__(256, 4) void y_gemm(const unsigned short* __restrict__ hsx,
                                                 const unsigned short* __restrict__ wyt,
                                                 const float* __restrict__ by,
                                                 float* __restrict__ y) {
  __shared__ __align__(16) unsigned short ha[64 * 256];  // 32KB
  int tid = threadIdx.x;
  int mt = blockIdx.x;
  int bb = mt >> 4;
  int t0 = (mt & 15) * 64;
  {
    int row = tid >> 2, q = tid & 3;
    const unsigned short* src = hsx + (size_t)(t0 + row) * (size_t)(BBATCH * 1024) + (size_t)bb * 1024;
#pragma unroll
    for (int i = 0; i < 8; ++i) {
      int u = q + i * 4;
      int4 vv = *(const int4*)(src + u * 8);
      *(int4*)((char*)ha + row * 512 + ((u * 16) ^ ((row & 7) << 4))) = vv;
    }
  }
  __syncthreads();
  int lane = tid & 63, wv = tid >> 6;
  int wr = wv >> 1, wc = wv & 1;
  int lr = lane & 15, hi = lane >> 4;
#pragma unroll 1
  for (int dblk = 0; dblk < 2; ++dblk) {
    f32x4 acc[2][4];
#pragma unroll
    for (int a = 0; a < 2; ++a)
#pragma unroll
      for (int b = 0; b < 4; ++b) acc[a][b] = (f32x4){0.f, 0.f, 0.f, 0.f};
    int dbase = dblk * 128 + wc * 64;
#pragma unroll
    for (int k0 = 0; k0 < 8; ++k0) {
      bf16x8 a[2], b[4];
#pragma unroll
      for (int mti = 0; mti < 2; ++mti) {
        int row = wr * 32 + mti * 16 + lr;
        a[mti] = *(const bf16x8*)((const char*)ha + row * 512 + ((k0 * 64 + hi * 16) ^ ((row & 7) << 4)));
      }
#pragma unroll
      for (int nt = 0; nt < 4; ++nt) {
        b[nt] = *(const bf16x8*)(wyt + (size_t)(dbase + nt * 16 + lr) * 256 + k0 * 32 + hi * 8);
#pragma unroll
        for (int mti = 0; mti < 2; ++mti)
          acc[mti][nt] = __builtin_amdgcn_mfma_f32_16x16x32_bf16(a[mti], b[nt], acc[mti][nt], 0, 0, 0);
      }
    }
#pragma unroll
    for (int mti = 0; mti < 2; ++mti)
#pragma unroll
      for (int nt = 0; nt < 4; ++nt) {
        int d = dbase + nt * 16 + lr;
        float bv = by[d];
#pragma unroll
        for (int r = 0; r < 4; ++r) {
          int trow = t0 + wr * 32 + mti * 16 + hi * 4 + r;
          y[((size_t)bb * TT + trow) * DD + d] = acc[mti][nt][r] + bv;
        }
      }
  }
}

// ---------------- launch ----------------
extern "C" void kernel_launch(void* const* d_in, const int* in_sizes, int n_in,
                              void* d_out, int out_size, void* d_ws, size_t ws_size,
                              hipStream_t stream) {
  const float* x   = (const float*)d_in[0];
  const float* wih = (const float*)d_in[1];
  const float* bih = (const float*)d_in[2];
  const float* whh = (const float*)d_in[3];
  const float* h0  = (const float*)d_in[4];
  const float* c0  = (const float*)d_in[5];
  const float* wy  = (const float*)d_in[6];
  const float* by  = (const float*)d_in[7];
  float* out = (float*)d_out;
  char* ws = (char*)d_ws;

  size_t off = 0;
  unsigned short* xw = (unsigned short*)(ws + off); off += (size_t)TT * BBATCH * G4 * 2;  // 512MB
  unsigned short* wbf = (unsigned short*)(ws + off); off += (size_t)G4 * DD * 2;          // 512KB
  unsigned short* wyt = (unsigned short*)(ws + off); off += (size_t)HH * DD * 2;          // 128KB
  signed char* wq = (signed char*)(ws + off); off += (size_t)G4 * HH;                     // 256KB
  float* dsc = (float*)(ws + off); off += G4 * 4;
  float* hh0 = (float*)(ws + off); off += G4 * 4;

  hipLaunchKernelGGL(prep_wih, dim3(256), dim3(256), 0, stream, wih, wbf);
  hipLaunchKernelGGL(prep_wyt, dim3(256), dim3(256), 0, stream, wy, wyt);
  hipLaunchKernelGGL(prep_whh, dim3(1024), dim3(64), 0, stream, whh, h0, wq, dsc, hh0);
  hipLaunchKernelGGL(xw_gemm, dim3(4096), dim3(256), 0, stream, x, wbf, bih, xw);
  hipLaunchKernelGGL(fix_xw0, dim3(1024), dim3(256), 0, stream, xw, hh0);
  hipLaunchKernelGGL(lstm_scan, dim3(64), dim3(512), 0, stream, xw, wq, dsc, c0, out);
  hipLaunchKernelGGL(y_gemm, dim3(4096), dim3(256), 0, stream, xw, wyt, by, out);
}

// Round 3
// 1849.250 us; speedup vs baseline: 2.7446x; 1.0372x over previous
//
#include <hip/hip_runtime.h>
#include <hip/hip_bf16.h>
#include <stdint.h>

#define TT 1024
#define BBATCH 256
#define DD 256
#define HH 256
#define G4 1024   // 4*H

typedef float f32x4 __attribute__((ext_vector_type(4)));
typedef short bf16x8 __attribute__((ext_vector_type(8)));
typedef int   i32x4  __attribute__((ext_vector_type(4)));

__device__ __forceinline__ float bf2f(unsigned int u) {
  union { unsigned int i; float f; } v; v.i = u << 16; return v.f;
}
__device__ __forceinline__ unsigned short f2bf(float f) {
  union { float f; unsigned int i; } v; v.f = f;
  unsigned int r = v.i + 0x7FFFu + ((v.i >> 16) & 1u);
  return (unsigned short)(r >> 16);
}

// ---------------- prep kernels ----------------

__global__ void prep_wih(const float* __restrict__ wih, unsigned short* __restrict__ out) {
  int i = blockIdx.x * 1024 + threadIdx.x * 4;
#pragma unroll
  for (int j = 0; j < 4; ++j) out[i + j] = f2bf(wih[i + j]);
}

__global__ void prep_wyt(const float* __restrict__ wy, unsigned short* __restrict__ wyt) {
  int k = blockIdx.x;
  int d = threadIdx.x;
  wyt[d * 256 + k] = f2bf(wy[k * 256 + d]);
}

// W_hh fp32 [1024 g][256 k] -> per-row-scaled int8 packed in MFMA B-frag order,
// dsc[g] = rowmax/127^2, hh0[g] = W_hh[g,:]·h0 (exact fp32).
__global__ void prep_whh(const float* __restrict__ whh, const float* __restrict__ h0,
                         signed char* __restrict__ wq, float* __restrict__ dsc,
                         float* __restrict__ hh0) {
  int g = blockIdx.x;
  int lane = threadIdx.x;
  float v[4];
  float mx = 0.f, acc = 0.f;
#pragma unroll
  for (int j = 0; j < 4; ++j) {
    v[j] = whh[g * 256 + lane * 4 + j];
    mx = fmaxf(mx, fabsf(v[j]));
    acc += v[j] * h0[lane * 4 + j];
  }
#pragma unroll
  for (int off = 32; off; off >>= 1) {
    mx  = fmaxf(mx, __shfl_xor(mx, off));
    acc = acc + __shfl_xor(acc, off);
  }
  mx = fmaxf(mx, 1e-12f);
  if (lane == 0) { dsc[g] = mx / (127.f * 127.f); hh0[g] = acc; }
  int sec = g >> 8, w = (g >> 5) & 7, m = (g >> 4) & 1, cl = g & 15;
  int nt = sec * 2 + m;
  float inv = 127.f / mx;
  int k0 = lane * 4;
  int kt = k0 >> 6, hi = (k0 >> 4) & 3, jj = k0 & 15;
  int base = ((((w * 8 + nt) * 4 + kt) * 64) + (cl | (hi << 4))) * 16 + jj;
#pragma unroll
  for (int j = 0; j < 4; ++j) {
    int q = (int)rintf(v[j] * inv);
    q = q > 127 ? 127 : (q < -127 ? -127 : q);
    wq[base + j] = (signed char)q;
  }
}

// xw[0][b][n*4+sec] += hh0[sec*256+n]
__global__ void fix_xw0(unsigned short* __restrict__ xw, const float* __restrict__ hh0) {
  int i = blockIdx.x * 256 + threadIdx.x;   // 262144 elems
  int pos = i & (G4 - 1);
  int n = pos >> 2, sec = pos & 3;
  xw[i] = f2bf(bf2f(xw[i]) + hh0[sec * 256 + n]);
}

// ---------------- phase 1: xw[t][b][n*4+sec] = (x[b,t,:] @ W_ih^T + b_ih), bf16, gate-packed ----------------
__global__ __launch_bounds__(256, 4) void xw_gemm(const float* __restrict__ x,
                                                  const unsigned short* __restrict__ wb,
                                                  const float* __restrict__ bih,
                                                  unsigned short* __restrict__ xw) {
  __shared__ __align__(16) unsigned short xa[64 * 256];  // 32KB, XOR-swizzled
  int tid = threadIdx.x;
  int mt = blockIdx.x;
  int bb = mt >> 4;
  int t0 = (mt & 15) * 64;
  {
    int row = tid >> 2, q = tid & 3;
    const float* src = x + ((size_t)bb * TT + (t0 + row)) * DD;
#pragma unroll
    for (int i = 0; i < 16; ++i) {
      int c4 = q + i * 4;
      float4 vv = *(const float4*)(src + c4 * 4);
      unsigned long long pk = (unsigned long long)f2bf(vv.x)
                            | ((unsigned long long)f2bf(vv.y) << 16)
                            | ((unsigned long long)f2bf(vv.z) << 32)
                            | ((unsigned long long)f2bf(vv.w) << 48);
      *(unsigned long long*)((char*)xa + row * 512 + ((c4 * 8) ^ ((row & 7) << 4))) = pk;
    }
  }
  __syncthreads();
  int lane = tid & 63, wv = tid >> 6;
  int wr = wv >> 1, wc = wv & 1;
  int lr = lane & 15, hi = lane >> 4;
#pragma unroll 1
  for (int gblk = 0; gblk < 8; ++gblk) {
    f32x4 acc[2][4];
#pragma unroll
    for (int a = 0; a < 2; ++a)
#pragma unroll
      for (int b = 0; b < 4; ++b) acc[a][b] = (f32x4){0.f, 0.f, 0.f, 0.f};
    int gbase = gblk * 128 + wc * 64;
    float bias[4];
#pragma unroll
    for (int nt = 0; nt < 4; ++nt) bias[nt] = bih[gbase + nt * 16 + lr];
#pragma unroll
    for (int k0 = 0; k0 < 8; ++k0) {
      bf16x8 a[2], b[4];
#pragma unroll
      for (int mti = 0; mti < 2; ++mti) {
        int row = wr * 32 + mti * 16 + lr;
        a[mti] = *(const bf16x8*)((const char*)xa + row * 512 + ((k0 * 64 + hi * 16) ^ ((row & 7) << 4)));
      }
#pragma unroll
      for (int nt = 0; nt < 4; ++nt) {
        b[nt] = *(const bf16x8*)(wb + (size_t)(gbase + nt * 16 + lr) * 256 + k0 * 32 + hi * 8);
#pragma unroll
        for (int mti = 0; mti < 2; ++mti)
          acc[mti][nt] = __builtin_amdgcn_mfma_f32_16x16x32_bf16(a[mti], b[nt], acc[mti][nt], 0, 0, 0);
      }
    }
#pragma unroll
    for (int mti = 0; mti < 2; ++mti)
#pragma unroll
      for (int nt = 0; nt < 4; ++nt) {
        int g = gbase + nt * 16 + lr;
        int g2 = ((g & 255) << 2) | (g >> 8);   // gate-packed position
#pragma unroll
        for (int r = 0; r < 4; ++r) {
          int trow = t0 + wr * 32 + mti * 16 + hi * 4 + r;
          xw[((size_t)trow * BBATCH + bb) * G4 + g2] = f2bf(acc[mti][nt][r] + bias[nt]);
        }
      }
  }
}

// ---------------- phase 2: the scan ----------------
// 64 blocks x 512 threads. Batch b in A/C row 4b -> every lane owns (batch=lane>>4, n-col=lane&15).
// xw loads: 2 x b64 per lane (gate-packed), prefetched 2 steps ahead (4-slot rotation).
__global__ __launch_bounds__(512, 2) void lstm_scan(unsigned short* xw,
                                                    const signed char* __restrict__ wq,
                                                    const float* __restrict__ dsc,
                                                    const float* __restrict__ c0,
                                                    float* __restrict__ out) {
  __shared__ __align__(16) signed char hq[2][4][64][16];  // 8KB, double-buffered int8 h A-frags
  int tid = threadIdx.x;
  int lane = tid & 63, wv = tid >> 6;
  int lr = lane & 15, q = lane >> 4;
  int b0 = blockIdx.x * 4;
  signed char* hqb = (signed char*)hq;

  // resident W_hh int8 B-frags
  i32x4 wf[8][4];
  {
    const i32x4* wp = (const i32x4*)(wq + (size_t)wv * (8 * 4 * 64 * 16));
#pragma unroll
    for (int nt = 0; nt < 8; ++nt)
#pragma unroll
      for (int kt = 0; kt < 4; ++kt) wf[nt][kt] = wp[(nt * 4 + kt) * 64 + lane];
  }
  float dr[4][2];
#pragma unroll
  for (int sec = 0; sec < 4; ++sec)
#pragma unroll
    for (int m = 0; m < 2; ++m) dr[sec][m] = dsc[sec * 256 + wv * 32 + m * 16 + lr];
  float cr[2], lh[2];
  cr[0] = c0[wv * 32 + lr];
  cr[1] = c0[wv * 32 + 16 + lr];
  lh[0] = lh[1] = 0.f;

  // zero both hq buffers
  *(i32x4*)(hqb + tid * 16) = (i32x4){0, 0, 0, 0};

  // per-lane pointers: loads are gate-packed (n*4+sec), stores (hs) at plain n
  unsigned short* ldb = xw + (size_t)(b0 + q) * G4 + (wv * 32 + lr) * 4;
  unsigned short* stb = xw + (size_t)(b0 + q) * G4 + wv * 32 + lr;
  unsigned long long xq[4][2];
#pragma unroll
  for (int s = 0; s < 2; ++s) {   // prologue: rows 0,1 -> slots 0,1
#pragma unroll
    for (int m = 0; m < 2; ++m) xq[s][m] = *(const unsigned long long*)(ldb + m * 64);
    ldb += (size_t)BBATCH * G4;
  }

  const int hqr = lane * 16;
  const int hqw = (wv >> 1) * 1024 + (wv & 1) * 512 + q * 64 + lr;
  const i32x4 zero4 = {0, 0, 0, 0};

  __syncthreads();  // hq zero visible

#define STEP(XC, XL, RB) { \
    XL[0] = *(const unsigned long long*)(ldb); \
    XL[1] = *(const unsigned long long*)(ldb + 64); \
    ldb += (size_t)BBATCH * G4; \
    i32x4 acc[8]; \
    _Pragma("unroll") \
    for (int kt = 0; kt < 4; ++kt) { \
      i32x4 af = *(const i32x4*)(hqb + (RB) + hqr + kt * 1024); \
      _Pragma("unroll") \
      for (int nt = 0; nt < 8; ++nt) \
        acc[nt] = __builtin_amdgcn_mfma_i32_16x16x64_i8(af, wf[nt][kt], kt == 0 ? zero4 : acc[nt], 0, 0, 0); \
    } \
    _Pragma("unroll") \
    for (int m = 0; m < 2; ++m) { \
      unsigned long long v = XC[m]; \
      float gi = fmaf(dr[0][m], (float)acc[0 + m][0], bf2f((unsigned int)(v & 0xffffu))); \
      float gf = fmaf(dr[1][m], (float)acc[2 + m][0], bf2f((unsigned int)((v >> 16) & 0xffffu))); \
      float gj = fmaf(dr[2][m], (float)acc[4 + m][0], bf2f((unsigned int)((v >> 32) & 0xffffu))); \
      float go = fmaf(dr[3][m], (float)acc[6 + m][0], bf2f((unsigned int)(v >> 48))); \
      float iv = __builtin_amdgcn_rcpf(1.f + __expf(-gi)); \
      float fv = __builtin_amdgcn_rcpf(1.f + __expf(-gf)); \
      float ov = __builtin_amdgcn_rcpf(1.f + __expf(-go)); \
      float jv = fmaf(-2.f, __builtin_amdgcn_rcpf(1.f + __expf(2.f * gj)), 1.f); \
      float cn = fmaf(fv, cr[m], iv * jv); \
      cr[m] = cn; \
      float th = fmaf(-2.f, __builtin_amdgcn_rcpf(1.f + __expf(2.f * cn)), 1.f); \
      float hn = ov * th; \
      lh[m] = hn; \
      hqb[((RB) ^ 4096) + hqw + m * 256] = (signed char)(int)rintf(hn * 127.f); \
      stb[m * 16] = f2bf(hn); \
    } \
    stb += (size_t)BBATCH * G4; \
    asm volatile("s_waitcnt lgkmcnt(0)" ::: "memory"); \
    __builtin_amdgcn_s_barrier(); \
  }

#pragma unroll 1
  for (int t = 0; t < TT; t += 4) {
    STEP(xq[0], xq[2], 0)
    STEP(xq[1], xq[3], 4096)
    STEP(xq[2], xq[0], 0)
    STEP(xq[3], xq[1], 4096)
  }
#undef STEP

  const size_t youts = (size_t)BBATCH * TT * DD;
#pragma unroll
  for (int m = 0; m < 2; ++m) {
    int kg = wv * 32 + m * 16 + lr;
    out[youts + (size_t)(b0 + q) * HH + kg] = lh[m];
    out[youts + (size_t)BBATCH * HH + (size_t)(b0 + q) * HH + kg] = cr[m];
  }
}

// ---------------- phase 3: y = hs @ W_y + b_y ----------------
__global__ __launch_bounds__(256, 4) void y_gemm(const unsigned short* __restrict__ hsx,
                                                 const unsigned short* __restrict__ wyt,
                                                 const float* __restrict__ by,
                                                 float* __restrict__ y) {
  __shared__ __align__(16) unsigned short ha[64 * 256];  // 32KB
  int tid = threadIdx.x;
  int mt = blockIdx.x;
  int bb = mt >> 4;
  int t0 = (mt & 15) * 64;
  {
    int row = tid >> 2, q = tid & 3;
    const unsigned short* src = hsx + (size_t)(t0 + row) * (size_t)(BBATCH * 1024) + (size_t)bb * 1024;
#pragma unroll
    for (int i = 0; i < 8; ++i) {
      int u = q + i * 4;
      int4 vv = *(const int4*)(src + u * 8);
      *(int4*)((char*)ha + row * 512 + ((u * 16) ^ ((row & 7) << 4))) = vv;
    }
  }
  __syncthreads();
  int lane = tid & 63, wv = tid >> 6;
  int wr = wv >> 1, wc = wv & 1;
  int lr = lane & 15, hi = lane >> 4;
#pragma unroll 1
  for (int dblk = 0; dblk < 2; ++dblk) {
    f32x4 acc[2][4];
#pragma unroll
    for (int a = 0; a < 2; ++a)
#pragma unroll
      for (int b = 0; b < 4; ++b) acc[a][b] = (f32x4){0.f, 0.f, 0.f, 0.f};
    int dbase = dblk * 128 + wc * 64;
#pragma unroll
    for (int k0 = 0; k0 < 8; ++k0) {
      bf16x8 a[2], b[4];
#pragma unroll
      for (int mti = 0; mti < 2; ++mti) {
        int row = wr * 32 + mti * 16 + lr;
        a[mti] = *(const bf16x8*)((const char*)ha + row * 512 + ((k0 * 64 + hi * 16) ^ ((row & 7) << 4)));
      }
#pragma unroll
      for (int nt = 0; nt < 4; ++nt) {
        b[nt] = *(const bf16x8*)(wyt + (size_t)(dbase + nt * 16 + lr) * 256 + k0 * 32 + hi * 8);
#pragma unroll
        for (int mti = 0; mti < 2; ++mti)
          acc[mti][nt] = __builtin_amdgcn_mfma_f32_16x16x32_bf16(a[mti], b[nt], acc[mti][nt], 0, 0, 0);
      }
    }
#pragma unroll
    for (int mti = 0; mti < 2; ++mti)
#pragma unroll
      for (int nt = 0; nt < 4; ++nt) {
        int d = dbase + nt * 16 + lr;
        float bv = by[d];
#pragma unroll
        for (int r = 0; r < 4; ++r) {
          int trow = t0 + wr * 32 + mti * 16 + hi * 4 + r;
          y[((size_t)bb * TT + trow) * DD + d] = acc[mti][nt][r] + bv;
        }
      }
  }
}

// ---------------- launch ----------------
extern "C" void kernel_launch(void* const* d_in, const int* in_sizes, int n_in,
                              void* d_out, int out_size, void* d_ws, size_t ws_size,
                              hipStream_t stream) {
  const float* x   = (const float*)d_in[0];
  const float* wih = (const float*)d_in[1];
  const float* bih = (const float*)d_in[2];
  const float* whh = (const float*)d_in[3];
  const float* h0  = (const float*)d_in[4];
  const float* c0  = (const float*)d_in[5];
  const float* wy  = (const float*)d_in[6];
  const float* by  = (const float*)d_in[7];
  float* out = (float*)d_out;
  char* ws = (char*)d_ws;

  size_t off = 0;
  unsigned short* xw = (unsigned short*)(ws + off); off += (size_t)TT * BBATCH * G4 * 2;  // 512MB
  unsigned short* wbf = (unsigned short*)(ws + off); off += (size_t)G4 * DD * 2;          // 512KB
  unsigned short* wyt = (unsigned short*)(ws + off); off += (size_t)HH * DD * 2;          // 128KB
  signed char* wq = (signed char*)(ws + off); off += (size_t)G4 * HH;                     // 256KB
  float* dsc = (float*)(ws + off); off += G4 * 4;
  float* hh0 = (float*)(ws + off); off += G4 * 4;

  hipLaunchKernelGGL(prep_wih, dim3(256), dim3(256), 0, stream, wih, wbf);
  hipLaunchKernelGGL(prep_wyt, dim3(256), dim3(256), 0, stream, wy, wyt);
  hipLaunchKernelGGL(prep_whh, dim3(1024), dim3(64), 0, stream, whh, h0, wq, dsc, hh0);
  hipLaunchKernelGGL(xw_gemm, dim3(4096), dim3(256), 0, stream, x, wbf, bih, xw);
  hipLaunchKernelGGL(fix_xw0, dim3(1024), dim3(256), 0, stream, xw, hh0);
  hipLaunchKernelGGL(lstm_scan, dim3(64), dim3(512), 0, stream, xw, wq, dsc, c0, out);
  hipLaunchKernelGGL(y_gemm, dim3(4096), dim3(256), 0, stream, xw, wyt, by, out);
}

// Round 4
// 1651.737 us; speedup vs baseline: 3.0727x; 1.1196x over previous
//
#include <hip/hip_runtime.h>
#include <hip/hip_bf16.h>
#include <stdint.h>

#define TT 1024
#define BBATCH 256
#define DD 256
#define HH 256
#define G4 1024   // 4*H

typedef float f32x4 __attribute__((ext_vector_type(4)));
typedef short bf16x8 __attribute__((ext_vector_type(8)));
typedef int   i32x4  __attribute__((ext_vector_type(4)));

__device__ __forceinline__ float bf2f(unsigned int u) {
  union { unsigned int i; float f; } v; v.i = u << 16; return v.f;
}
__device__ __forceinline__ unsigned short f2bf(float f) {
  union { float f; unsigned int i; } v; v.f = f;
  unsigned int r = v.i + 0x7FFFu + ((v.i >> 16) & 1u);
  return (unsigned short)(r >> 16);
}

// ---------------- prep kernels ----------------

__global__ void prep_wih(const float* __restrict__ wih, unsigned short* __restrict__ out) {
  int i = blockIdx.x * 1024 + threadIdx.x * 4;
#pragma unroll
  for (int j = 0; j < 4; ++j) out[i + j] = f2bf(wih[i + j]);
}

__global__ void prep_wyt(const float* __restrict__ wy, unsigned short* __restrict__ wyt) {
  int k = blockIdx.x;
  int d = threadIdx.x;
  wyt[d * 256 + k] = f2bf(wy[k * 256 + d]);
}

// W_hh fp32 [1024 g][256 k] -> per-row-scaled int8 packed in MFMA B-frag order for the
// 16-wave scan: g = sec*256 + n, n = w*16 + cl. Frag slot [((w*4+sec)*4+kt)*64 + lane],
// lane = cl|(hi<<4), element byte j = k&15, hi=(k>>4)&3, kt=k>>6.
__global__ void prep_whh(const float* __restrict__ whh, const float* __restrict__ h0,
                         signed char* __restrict__ wq, float* __restrict__ dsc,
                         float* __restrict__ hh0) {
  int g = blockIdx.x;
  int lane = threadIdx.x;
  float v[4];
  float mx = 0.f, acc = 0.f;
#pragma unroll
  for (int j = 0; j < 4; ++j) {
    v[j] = whh[g * 256 + lane * 4 + j];
    mx = fmaxf(mx, fabsf(v[j]));
    acc += v[j] * h0[lane * 4 + j];
  }
#pragma unroll
  for (int off = 32; off; off >>= 1) {
    mx  = fmaxf(mx, __shfl_xor(mx, off));
    acc = acc + __shfl_xor(acc, off);
  }
  mx = fmaxf(mx, 1e-12f);
  if (lane == 0) { dsc[g] = mx / (127.f * 127.f); hh0[g] = acc; }
  int sec = g >> 8, w = (g >> 4) & 15, cl = g & 15;
  float inv = 127.f / mx;
  int k0 = lane * 4;
  int kt = k0 >> 6, hi = (k0 >> 4) & 3, jj = k0 & 15;
  int base = (((w * 4 + sec) * 4 + kt) * 64 + (cl | (hi << 4))) * 16 + jj;
#pragma unroll
  for (int j = 0; j < 4; ++j) {
    int q = (int)rintf(v[j] * inv);
    q = q > 127 ? 127 : (q < -127 ? -127 : q);
    wq[base + j] = (signed char)q;
  }
}

// xw[0][b][n*4+sec] += hh0[sec*256+n]
__global__ void fix_xw0(unsigned short* __restrict__ xw, const float* __restrict__ hh0) {
  int i = blockIdx.x * 256 + threadIdx.x;   // 262144 elems
  int pos = i & (G4 - 1);
  int n = pos >> 2, sec = pos & 3;
  xw[i] = f2bf(bf2f(xw[i]) + hh0[sec * 256 + n]);
}

// ---------------- phase 1: xw[t][b][n*4+sec] = (x[b,t,:] @ W_ih^T + b_ih), bf16, gate-packed ----
// grid 4096, block 256. Outer nh halves; inner accumulates all 4 secs so the store packs
// 4 gate values into one u64 -> 8B/lane fully coalesced.
__global__ __launch_bounds__(256, 2) void xw_gemm(const float* __restrict__ x,
                                                  const unsigned short* __restrict__ wb,
                                                  const float* __restrict__ bih,
                                                  unsigned short* __restrict__ xw) {
  __shared__ __align__(16) unsigned short xa[64 * 256];  // 32KB, XOR-swizzled
  int tid = threadIdx.x;
  int mt = blockIdx.x;
  int bb = mt >> 4;
  int t0 = (mt & 15) * 64;
  {
    int row = tid >> 2, q = tid & 3;
    const float* src = x + ((size_t)bb * TT + (t0 + row)) * DD;
#pragma unroll
    for (int i = 0; i < 16; ++i) {
      int c4 = q + i * 4;
      float4 vv = *(const float4*)(src + c4 * 4);
      unsigned long long pk = (unsigned long long)f2bf(vv.x)
                            | ((unsigned long long)f2bf(vv.y) << 16)
                            | ((unsigned long long)f2bf(vv.z) << 32)
                            | ((unsigned long long)f2bf(vv.w) << 48);
      *(unsigned long long*)((char*)xa + row * 512 + ((c4 * 8) ^ ((row & 7) << 4))) = pk;
    }
  }
  __syncthreads();
  int lane = tid & 63, wv = tid >> 6;
  int wr = wv >> 1, wc = wv & 1;
  int lr = lane & 15, hi = lane >> 4;
#pragma unroll 1
  for (int nh = 0; nh < 2; ++nh) {
    f32x4 acc[4][2][4];
#pragma unroll
    for (int s = 0; s < 4; ++s)
#pragma unroll
      for (int a = 0; a < 2; ++a)
#pragma unroll
        for (int b = 0; b < 4; ++b) acc[s][a][b] = (f32x4){0.f, 0.f, 0.f, 0.f};
    int nbase = nh * 128 + wc * 64;
#pragma unroll
    for (int k0 = 0; k0 < 8; ++k0) {
      bf16x8 a[2];
#pragma unroll
      for (int mti = 0; mti < 2; ++mti) {
        int row = wr * 32 + mti * 16 + lr;
        a[mti] = *(const bf16x8*)((const char*)xa + row * 512 + ((k0 * 64 + hi * 16) ^ ((row & 7) << 4)));
      }
#pragma unroll
      for (int sec = 0; sec < 4; ++sec) {
#pragma unroll
        for (int nt = 0; nt < 4; ++nt) {
          bf16x8 bfr = *(const bf16x8*)(wb + (size_t)(sec * 256 + nbase + nt * 16 + lr) * 256 + k0 * 32 + hi * 8);
#pragma unroll
          for (int mti = 0; mti < 2; ++mti)
            acc[sec][mti][nt] = __builtin_amdgcn_mfma_f32_16x16x32_bf16(a[mti], bfr, acc[sec][mti][nt], 0, 0, 0);
        }
      }
    }
    // epilogue: per (mti, nt, r) pack 4 secs -> u64, contiguous 8B/lane stores
#pragma unroll
    for (int nt = 0; nt < 4; ++nt) {
      int n = nbase + nt * 16 + lr;
      float bias[4];
#pragma unroll
      for (int sec = 0; sec < 4; ++sec) bias[sec] = bih[sec * 256 + n];
#pragma unroll
      for (int mti = 0; mti < 2; ++mti) {
#pragma unroll
        for (int r = 0; r < 4; ++r) {
          int trow = t0 + wr * 32 + mti * 16 + hi * 4 + r;
          unsigned long long pk =
              (unsigned long long)f2bf(acc[0][mti][nt][r] + bias[0])
            | ((unsigned long long)f2bf(acc[1][mti][nt][r] + bias[1]) << 16)
            | ((unsigned long long)f2bf(acc[2][mti][nt][r] + bias[2]) << 32)
            | ((unsigned long long)f2bf(acc[3][mti][nt][r] + bias[3]) << 48);
          *(unsigned long long*)(xw + ((size_t)trow * BBATCH + bb) * G4 + (size_t)n * 4) = pk;
        }
      }
    }
  }
}

// ---------------- phase 2: the scan ----------------
// 64 blocks x 1024 threads (16 waves, 4/SIMD). Block owns 4 batches (A/C rows 4b).
// Wave wv owns n-range wv*16..+16, all 4 gates (nt=sec). Per lane per step:
// 16 MFMA, 1 gate-set, 1 u64 xw load (prefetched 2 ahead), 1 hq byte, 1 hs bf16.
__global__ __launch_bounds__(1024, 1) void lstm_scan(unsigned short* xw,
                                                     const signed char* __restrict__ wq,
                                                     const float* __restrict__ dsc,
                                                     const float* __restrict__ c0,
                                                     float* __restrict__ out) {
  __shared__ __align__(16) signed char hq[2][4][64][16];  // 8KB, double-buffered int8 h A-frags
  int tid = threadIdx.x;
  int lane = tid & 63, wv = tid >> 6;
  int lr = lane & 15, q = lane >> 4;
  int b0 = blockIdx.x * 4;
  signed char* hqb = (signed char*)hq;
  int nn = wv * 16 + lr;

  // resident W_hh int8 B-frags: 16 i32x4 = 64 VGPRs
  i32x4 wf[4][4];
  {
    const i32x4* wp = (const i32x4*)wq;
#pragma unroll
    for (int sec = 0; sec < 4; ++sec)
#pragma unroll
      for (int kt = 0; kt < 4; ++kt) wf[sec][kt] = wp[((wv * 4 + sec) * 4 + kt) * 64 + lane];
  }
  float dr[4];
#pragma unroll
  for (int sec = 0; sec < 4; ++sec) dr[sec] = dsc[sec * 256 + nn];
  float cr = c0[nn], lh = 0.f;

  // zero both hq buffers (8KB = 1024 threads * 8B)
  *(unsigned long long*)(hqb + tid * 8) = 0ull;

  // per-lane pointers
  unsigned short* ldb = xw + (size_t)(b0 + q) * G4 + (size_t)nn * 4;
  unsigned short* stb = xw + (size_t)(b0 + q) * G4 + nn;
  unsigned long long xq[4];
#pragma unroll
  for (int s = 0; s < 2; ++s) {
    xq[s] = *(const unsigned long long*)ldb;
    ldb += (size_t)BBATCH * G4;
  }

  const int hqr = lane * 16;
  // producer write: kt = wv>>2, hi = wv&3, row = 4q, byte j = lr
  const int hqw = (wv >> 2) * 1024 + (wv & 3) * 256 + q * 64 + lr;
  const i32x4 zero4 = {0, 0, 0, 0};

  __syncthreads();  // hq zero visible

#define STEP(XC, XL, RB) { \
    XL = *(const unsigned long long*)ldb; \
    ldb += (size_t)BBATCH * G4; \
    i32x4 acc[4]; \
    __builtin_amdgcn_s_setprio(1); \
    _Pragma("unroll") \
    for (int kt = 0; kt < 4; ++kt) { \
      i32x4 af = *(const i32x4*)(hqb + (RB) + hqr + kt * 1024); \
      _Pragma("unroll") \
      for (int sec = 0; sec < 4; ++sec) \
        acc[sec] = __builtin_amdgcn_mfma_i32_16x16x64_i8(af, wf[sec][kt], kt == 0 ? zero4 : acc[sec], 0, 0, 0); \
    } \
    __builtin_amdgcn_s_setprio(0); \
    { \
      unsigned long long v = XC; \
      float gi = fmaf(dr[0], (float)acc[0][0], bf2f((unsigned int)(v & 0xffffu))); \
      float gf = fmaf(dr[1], (float)acc[1][0], bf2f((unsigned int)((v >> 16) & 0xffffu))); \
      float gj = fmaf(dr[2], (float)acc[2][0], bf2f((unsigned int)((v >> 32) & 0xffffu))); \
      float go = fmaf(dr[3], (float)acc[3][0], bf2f((unsigned int)(v >> 48))); \
      float iv = __builtin_amdgcn_rcpf(1.f + __expf(-gi)); \
      float fv = __builtin_amdgcn_rcpf(1.f + __expf(-gf)); \
      float ov = __builtin_amdgcn_rcpf(1.f + __expf(-go)); \
      float jv = fmaf(-2.f, __builtin_amdgcn_rcpf(1.f + __expf(2.f * gj)), 1.f); \
      float cn = fmaf(fv, cr, iv * jv); \
      cr = cn; \
      float th = fmaf(-2.f, __builtin_amdgcn_rcpf(1.f + __expf(2.f * cn)), 1.f); \
      float hn = ov * th; \
      lh = hn; \
      hqb[((RB) ^ 4096) + hqw] = (signed char)(int)rintf(hn * 127.f); \
      stb[0] = f2bf(hn); \
    } \
    stb += (size_t)BBATCH * G4; \
    asm volatile("s_waitcnt lgkmcnt(0)" ::: "memory"); \
    __builtin_amdgcn_s_barrier(); \
  }

#pragma unroll 1
  for (int t = 0; t < TT; t += 4) {
    STEP(xq[0], xq[2], 0)
    STEP(xq[1], xq[3], 4096)
    STEP(xq[2], xq[0], 0)
    STEP(xq[3], xq[1], 4096)
  }
#undef STEP

  const size_t youts = (size_t)BBATCH * TT * DD;
  out[youts + (size_t)(b0 + q) * HH + nn] = lh;
  out[youts + (size_t)BBATCH * HH + (size_t)(b0 + q) * HH + nn] = cr;
}

// ---------------- phase 3: y = hs @ W_y + b_y ----------------
__global__ __launch_bounds__(256, 4) void y_gemm(const unsigned short* __restrict__ hsx,
                                                 const unsigned short* __restrict__ wyt,
                                                 const float* __restrict__ by,
                                                 float* __restrict__ y) {
  __shared__ __align__(16) unsigned short ha[64 * 256];  // 32KB
  int tid = threadIdx.x;
  int mt = blockIdx.x;
  int bb = mt >> 4;
  int t0 = (mt & 15) * 64;
  {
    int row = tid >> 2, q = tid & 3;
    const unsigned short* src = hsx + (size_t)(t0 + row) * (size_t)(BBATCH * 1024) + (size_t)bb * 1024;
#pragma unroll
    for (int i = 0; i < 8; ++i) {
      int u = q + i * 4;
      int4 vv = *(const int4*)(src + u * 8);
      *(int4*)((char*)ha + row * 512 + ((u * 16) ^ ((row & 7) << 4))) = vv;
    }
  }
  __syncthreads();
  int lane = tid & 63, wv = tid >> 6;
  int wr = wv >> 1, wc = wv & 1;
  int lr = lane & 15, hi = lane >> 4;
#pragma unroll 1
  for (int dblk = 0; dblk < 2; ++dblk) {
    f32x4 acc[2][4];
#pragma unroll
    for (int a = 0; a < 2; ++a)
#pragma unroll
      for (int b = 0; b < 4; ++b) acc[a][b] = (f32x4){0.f, 0.f, 0.f, 0.f};
    int dbase = dblk * 128 + wc * 64;
#pragma unroll
    for (int k0 = 0; k0 < 8; ++k0) {
      bf16x8 a[2], b[4];
#pragma unroll
      for (int mti = 0; mti < 2; ++mti) {
        int row = wr * 32 + mti * 16 + lr;
        a[mti] = *(const bf16x8*)((const char*)ha + row * 512 + ((k0 * 64 + hi * 16) ^ ((row & 7) << 4)));
      }
#pragma unroll
      for (int nt = 0; nt < 4; ++nt) {
        b[nt] = *(const bf16x8*)(wyt + (size_t)(dbase + nt * 16 + lr) * 256 + k0 * 32 + hi * 8);
#pragma unroll
        for (int mti = 0; mti < 2; ++mti)
          acc[mti][nt] = __builtin_amdgcn_mfma_f32_16x16x32_bf16(a[mti], b[nt], acc[mti][nt], 0, 0, 0);
      }
    }
#pragma unroll
    for (int mti = 0; mti < 2; ++mti)
#pragma unroll
      for (int nt = 0; nt < 4; ++nt) {
        int d = dbase + nt * 16 + lr;
        float bv = by[d];
#pragma unroll
        for (int r = 0; r < 4; ++r) {
          int trow = t0 + wr * 32 + mti * 16 + hi * 4 + r;
          y[((size_t)bb * TT + trow) * DD + d] = acc[mti][nt][r] + bv;
        }
      }
  }
}

// ---------------- launch ----------------
extern "C" void kernel_launch(void* const* d_in, const int* in_sizes, int n_in,
                              void* d_out, int out_size, void* d_ws, size_t ws_size,
                              hipStream_t stream) {
  const float* x   = (const float*)d_in[0];
  const float* wih = (const float*)d_in[1];
  const float* bih = (const float*)d_in[2];
  const float* whh = (const float*)d_in[3];
  const float* h0  = (const float*)d_in[4];
  const float* c0  = (const float*)d_in[5];
  const float* wy  = (const float*)d_in[6];
  const float* by  = (const float*)d_in[7];
  float* out = (float*)d_out;
  char* ws = (char*)d_ws;

  size_t off = 0;
  unsigned short* xw = (unsigned short*)(ws + off);
  off += (size_t)(TT + 2) * BBATCH * G4 * 2;   // 512MB + 2-row prefetch slack
  unsigned short* wbf = (unsigned short*)(ws + off); off += (size_t)G4 * DD * 2;
  unsigned short* wyt = (unsigned short*)(ws + off); off += (size_t)HH * DD * 2;
  signed char* wq = (signed char*)(ws + off); off += (size_t)G4 * HH;
  float* dsc = (float*)(ws + off); off += G4 * 4;
  float* hh0 = (float*)(ws + off); off += G4 * 4;

  hipLaunchKernelGGL(prep_wih, dim3(256), dim3(256), 0, stream, wih, wbf);
  hipLaunchKernelGGL(prep_wyt, dim3(256), dim3(256), 0, stream, wy, wyt);
  hipLaunchKernelGGL(prep_whh, dim3(1024), dim3(64), 0, stream, whh, h0, wq, dsc, hh0);
  hipLaunchKernelGGL(xw_gemm, dim3(4096), dim3(256), 0, stream, x, wbf, bih, xw);
  hipLaunchKernelGGL(fix_xw0, dim3(1024), dim3(256), 0, stream, xw, hh0);
  hipLaunchKernelGGL(lstm_scan, dim3(64), dim3(1024), 0, stream, xw, wq, dsc, c0, out);
  hipLaunchKernelGGL(y_gemm, dim3(4096), dim3(256), 0, stream, xw, wyt, by, out);
}

// Round 5
// 1492.969 us; speedup vs baseline: 3.3995x; 1.1063x over previous
//
#include <hip/hip_runtime.h>
#include <hip/hip_bf16.h>
#include <stdint.h>

#define TT 1024
#define BBATCH 256
#define DD 256
#define HH 256
#define G4 1024   // 4*H

typedef float f32x4 __attribute__((ext_vector_type(4)));
typedef short bf16x8 __attribute__((ext_vector_type(8)));
typedef int   i32x4  __attribute__((ext_vector_type(4)));

__device__ __forceinline__ float bf2f(unsigned int u) {
  union { unsigned int i; float f; } v; v.i = u << 16; return v.f;
}
__device__ __forceinline__ unsigned short f2bf(float f) {
  union { float f; unsigned int i; } v; v.f = f;
  unsigned int r = v.i + 0x7FFFu + ((v.i >> 16) & 1u);
  return (unsigned short)(r >> 16);
}

// ---------------- prep kernels ----------------

// W_ih fp32 [1024 g][256 d] -> bf16 packed in MFMA B-frag order for xw_gemm:
// g = sec*256 + n; n = nh*128 + wc*64 + nt*16 + lr; d: k0=d>>5, hi=(d>>3)&3, el=d&7.
// slot = (((((nh*2+wc)*4+sec)*4+nt)*8+k0)*64 + (lr|hi<<4))*8 + el  -> wave loads are contiguous 1KB.
__global__ void prep_wih(const float* __restrict__ wih, unsigned short* __restrict__ out) {
  int g = blockIdx.x;          // 0..1023
  int lane = threadIdx.x;      // 0..63
  int sec = g >> 8, n = g & 255;
  int nh = n >> 7, wc = (n >> 6) & 1, nt = (n >> 4) & 3, lr = n & 15;
  int d0 = lane * 4;
  int k0 = d0 >> 5, hi = (d0 >> 3) & 3;
  size_t idx = ((((((size_t)nh * 2 + wc) * 4 + sec) * 4 + nt) * 8 + k0) * 64 + (lr | (hi << 4))) * 8 + (d0 & 7);
#pragma unroll
  for (int j = 0; j < 4; ++j) out[idx + j] = f2bf(wih[g * 256 + d0 + j]);
}

__global__ void prep_wyt(const float* __restrict__ wy, unsigned short* __restrict__ wyt) {
  int k = blockIdx.x;
  int d = threadIdx.x;
  wyt[d * 256 + k] = f2bf(wy[k * 256 + d]);
}

// W_hh fp32 [1024 g][256 k] -> per-row-scaled int8 packed in MFMA B-frag order for the
// 16-wave scan: g = sec*256 + n, n = w*16 + cl. Frag slot [((w*4+sec)*4+kt)*64 + lane].
__global__ void prep_whh(const float* __restrict__ whh, const float* __restrict__ h0,
                         signed char* __restrict__ wq, float* __restrict__ dsc,
                         float* __restrict__ hh0) {
  int g = blockIdx.x;
  int lane = threadIdx.x;
  float v[4];
  float mx = 0.f, acc = 0.f;
#pragma unroll
  for (int j = 0; j < 4; ++j) {
    v[j] = whh[g * 256 + lane * 4 + j];
    mx = fmaxf(mx, fabsf(v[j]));
    acc += v[j] * h0[lane * 4 + j];
  }
#pragma unroll
  for (int off = 32; off; off >>= 1) {
    mx  = fmaxf(mx, __shfl_xor(mx, off));
    acc = acc + __shfl_xor(acc, off);
  }
  mx = fmaxf(mx, 1e-12f);
  if (lane == 0) { dsc[g] = mx / (127.f * 127.f); hh0[g] = acc; }
  int sec = g >> 8, w = (g >> 4) & 15, cl = g & 15;
  float inv = 127.f / mx;
  int k0 = lane * 4;
  int kt = k0 >> 6, hi = (k0 >> 4) & 3, jj = k0 & 15;
  int base = (((w * 4 + sec) * 4 + kt) * 64 + (cl | (hi << 4))) * 16 + jj;
#pragma unroll
  for (int j = 0; j < 4; ++j) {
    int q = (int)rintf(v[j] * inv);
    q = q > 127 ? 127 : (q < -127 ? -127 : q);
    wq[base + j] = (signed char)q;
  }
}

// xw[0][b][n*4+sec] += hh0[sec*256+n]
__global__ void fix_xw0(unsigned short* __restrict__ xw, const float* __restrict__ hh0) {
  int i = blockIdx.x * 256 + threadIdx.x;   // 262144 elems
  int pos = i & (G4 - 1);
  int n = pos >> 2, sec = pos & 3;
  xw[i] = f2bf(bf2f(xw[i]) + hh0[sec * 256 + n]);
}

// ---------------- phase 1: xw[t][b][n*4+sec] = (x[b,t,:] @ W_ih^T + b_ih), bf16, gate-packed ----
// grid 4096, block 256. Frag-ordered wb: every B-load is a contiguous 1KB wave stream.
__global__ __launch_bounds__(256, 2) void xw_gemm(const float* __restrict__ x,
                                                  const unsigned short* __restrict__ wb,
                                                  const float* __restrict__ bih,
                                                  unsigned short* __restrict__ xw) {
  __shared__ __align__(16) unsigned short xa[64 * 256];  // 32KB, XOR-swizzled
  int tid = threadIdx.x;
  int mt = blockIdx.x;
  int bb = mt >> 4;
  int t0 = (mt & 15) * 64;
  {
    int row = tid >> 2, q = tid & 3;
    const float* src = x + ((size_t)bb * TT + (t0 + row)) * DD;
#pragma unroll
    for (int i = 0; i < 16; ++i) {
      int c4 = q + i * 4;
      float4 vv = *(const float4*)(src + c4 * 4);
      unsigned long long pk = (unsigned long long)f2bf(vv.x)
                            | ((unsigned long long)f2bf(vv.y) << 16)
                            | ((unsigned long long)f2bf(vv.z) << 32)
                            | ((unsigned long long)f2bf(vv.w) << 48);
      *(unsigned long long*)((char*)xa + row * 512 + ((c4 * 8) ^ ((row & 7) << 4))) = pk;
    }
  }
  __syncthreads();
  int lane = tid & 63, wv = tid >> 6;
  int wr = wv >> 1, wc = wv & 1;
  int lr = lane & 15, hi = lane >> 4;
#pragma unroll 1
  for (int nh = 0; nh < 2; ++nh) {
    const bf16x8* wfrag = (const bf16x8*)(wb + (size_t)(nh * 2 + wc) * (4 * 4 * 8 * 64 * 8));
    f32x4 acc[4][2][4];
#pragma unroll
    for (int s = 0; s < 4; ++s)
#pragma unroll
      for (int a = 0; a < 2; ++a)
#pragma unroll
        for (int b = 0; b < 4; ++b) acc[s][a][b] = (f32x4){0.f, 0.f, 0.f, 0.f};
    int nbase = nh * 128 + wc * 64;
#pragma unroll
    for (int k0 = 0; k0 < 8; ++k0) {
      bf16x8 a[2];
#pragma unroll
      for (int mti = 0; mti < 2; ++mti) {
        int row = wr * 32 + mti * 16 + lr;
        a[mti] = *(const bf16x8*)((const char*)xa + row * 512 + ((k0 * 64 + hi * 16) ^ ((row & 7) << 4)));
      }
#pragma unroll
      for (int sec = 0; sec < 4; ++sec) {
#pragma unroll
        for (int nt = 0; nt < 4; ++nt) {
          bf16x8 bfr = wfrag[((sec * 4 + nt) * 8 + k0) * 64 + lane];
#pragma unroll
          for (int mti = 0; mti < 2; ++mti)
            acc[sec][mti][nt] = __builtin_amdgcn_mfma_f32_16x16x32_bf16(a[mti], bfr, acc[sec][mti][nt], 0, 0, 0);
        }
      }
    }
    // epilogue: per (mti, nt, r) pack 4 secs -> u64, contiguous 8B/lane stores
#pragma unroll
    for (int nt = 0; nt < 4; ++nt) {
      int n = nbase + nt * 16 + lr;
      float bias[4];
#pragma unroll
      for (int sec = 0; sec < 4; ++sec) bias[sec] = bih[sec * 256 + n];
#pragma unroll
      for (int mti = 0; mti < 2; ++mti) {
#pragma unroll
        for (int r = 0; r < 4; ++r) {
          int trow = t0 + wr * 32 + mti * 16 + hi * 4 + r;
          unsigned long long pk =
              (unsigned long long)f2bf(acc[0][mti][nt][r] + bias[0])
            | ((unsigned long long)f2bf(acc[1][mti][nt][r] + bias[1]) << 16)
            | ((unsigned long long)f2bf(acc[2][mti][nt][r] + bias[2]) << 32)
            | ((unsigned long long)f2bf(acc[3][mti][nt][r] + bias[3]) << 48);
          *(unsigned long long*)(xw + ((size_t)trow * BBATCH + bb) * G4 + (size_t)n * 4) = pk;
        }
      }
    }
  }
}

// ---------------- phase 2: the scan ----------------
// 64 blocks x 1024 threads (16 waves, 4/SIMD). Block owns 4 batches (A/C rows 4b).
// Wave wv owns n-range wv*16..+16, all 4 gates (nt=sec). Per lane per step:
// 16 MFMA, 1 gate-set, 1 u64 xw load (prefetched 2 ahead), 1 hq byte, 1 hs bf16.
__global__ __launch_bounds__(1024, 1) void lstm_scan(unsigned short* xw,
                                                     const signed char* __restrict__ wq,
                                                     const float* __restrict__ dsc,
                                                     const float* __restrict__ c0,
                                                     float* __restrict__ out) {
  __shared__ __align__(16) signed char hq[2][4][64][16];  // 8KB, double-buffered int8 h A-frags
  int tid = threadIdx.x;
  int lane = tid & 63, wv = tid >> 6;
  int lr = lane & 15, q = lane >> 4;
  int b0 = blockIdx.x * 4;
  signed char* hqb = (signed char*)hq;
  int nn = wv * 16 + lr;

  // resident W_hh int8 B-frags: 16 i32x4 = 64 VGPRs
  i32x4 wf[4][4];
  {
    const i32x4* wp = (const i32x4*)wq;
#pragma unroll
    for (int sec = 0; sec < 4; ++sec)
#pragma unroll
      for (int kt = 0; kt < 4; ++kt) wf[sec][kt] = wp[((wv * 4 + sec) * 4 + kt) * 64 + lane];
  }
  float dr[4];
#pragma unroll
  for (int sec = 0; sec < 4; ++sec) dr[sec] = dsc[sec * 256 + nn];
  float cr = c0[nn], lh = 0.f;

  // zero both hq buffers (8KB = 1024 threads * 8B)
  *(unsigned long long*)(hqb + tid * 8) = 0ull;

  // per-lane pointers
  unsigned short* ldb = xw + (size_t)(b0 + q) * G4 + (size_t)nn * 4;
  unsigned short* stb = xw + (size_t)(b0 + q) * G4 + nn;
  unsigned long long xq[4];
#pragma unroll
  for (int s = 0; s < 2; ++s) {
    xq[s] = *(const unsigned long long*)ldb;
    ldb += (size_t)BBATCH * G4;
  }

  const int hqr = lane * 16;
  // producer write: kt = wv>>2, hi = wv&3, row = 4q, byte j = lr
  const int hqw = (wv >> 2) * 1024 + (wv & 3) * 256 + q * 64 + lr;
  const i32x4 zero4 = {0, 0, 0, 0};

  __syncthreads();  // hq zero visible

#define STEP(XC, XL, RB) { \
    XL = *(const unsigned long long*)ldb; \
    ldb += (size_t)BBATCH * G4; \
    i32x4 acc[4]; \
    __builtin_amdgcn_s_setprio(1); \
    _Pragma("unroll") \
    for (int kt = 0; kt < 4; ++kt) { \
      i32x4 af = *(const i32x4*)(hqb + (RB) + hqr + kt * 1024); \
      _Pragma("unroll") \
      for (int sec = 0; sec < 4; ++sec) \
        acc[sec] = __builtin_amdgcn_mfma_i32_16x16x64_i8(af, wf[sec][kt], kt == 0 ? zero4 : acc[sec], 0, 0, 0); \
    } \
    __builtin_amdgcn_s_setprio(0); \
    { \
      unsigned long long v = XC; \
      float gi = fmaf(dr[0], (float)acc[0][0], bf2f((unsigned int)(v & 0xffffu))); \
      float gf = fmaf(dr[1], (float)acc[1][0], bf2f((unsigned int)((v >> 16) & 0xffffu))); \
      float gj = fmaf(dr[2], (float)acc[2][0], bf2f((unsigned int)((v >> 32) & 0xffffu))); \
      float go = fmaf(dr[3], (float)acc[3][0], bf2f((unsigned int)(v >> 48))); \
      float iv = __builtin_amdgcn_rcpf(1.f + __expf(-gi)); \
      float fv = __builtin_amdgcn_rcpf(1.f + __expf(-gf)); \
      float ov = __builtin_amdgcn_rcpf(1.f + __expf(-go)); \
      float jv = fmaf(-2.f, __builtin_amdgcn_rcpf(1.f + __expf(2.f * gj)), 1.f); \
      float cn = fmaf(fv, cr, iv * jv); \
      cr = cn; \
      float th = fmaf(-2.f, __builtin_amdgcn_rcpf(1.f + __expf(2.f * cn)), 1.f); \
      float hn = ov * th; \
      lh = hn; \
      hqb[((RB) ^ 4096) + hqw] = (signed char)(int)rintf(hn * 127.f); \
      stb[0] = f2bf(hn); \
    } \
    stb += (size_t)BBATCH * G4; \
    asm volatile("s_waitcnt lgkmcnt(0)" ::: "memory"); \
    __builtin_amdgcn_s_barrier(); \
  }

#pragma unroll 1
  for (int t = 0; t < TT; t += 4) {
    STEP(xq[0], xq[2], 0)
    STEP(xq[1], xq[3], 4096)
    STEP(xq[2], xq[0], 0)
    STEP(xq[3], xq[1], 4096)
  }
#undef STEP

  const size_t youts = (size_t)BBATCH * TT * DD;
  out[youts + (size_t)(b0 + q) * HH + nn] = lh;
  out[youts + (size_t)BBATCH * HH + (size_t)(b0 + q) * HH + nn] = cr;
}

// ---------------- phase 3: y = hs @ W_y + b_y ----------------
__global__ __launch_bounds__(256, 4) void y_gemm(const unsigned short* __restrict__ hsx,
                                                 const unsigned short* __restrict__ wyt,
                                                 const float* __restrict__ by,
                                                 float* __restrict__ y) {
  __shared__ __align__(16) unsigned short ha[64 * 256];  // 32KB
  int tid = threadIdx.x;
  int mt = blockIdx.x;
  int bb = mt >> 4;
  int t0 = (mt & 15) * 64;
  {
    int row = tid >> 2, q = tid & 3;
    const unsigned short* src = hsx + (size_t)(t0 + row) * (size_t)(BBATCH * 1024) + (size_t)bb * 1024;
#pragma unroll
    for (int i = 0; i < 8; ++i) {
      int u = q + i * 4;
      int4 vv = *(const int4*)(src + u * 8);
      *(int4*)((char*)ha + row * 512 + ((u * 16) ^ ((row & 7) << 4))) = vv;
    }
  }
  __syncthreads();
  int lane = tid & 63, wv = tid >> 6;
  int wr = wv >> 1, wc = wv & 1;
  int lr = lane & 15, hi = lane >> 4;
#pragma unroll 1
  for (int dblk = 0; dblk < 2; ++dblk) {
    f32x4 acc[2][4];
#pragma unroll
    for (int a = 0; a < 2; ++a)
#pragma unroll
      for (int b = 0; b < 4; ++b) acc[a][b] = (f32x4){0.f, 0.f, 0.f, 0.f};
    int dbase = dblk * 128 + wc * 64;
#pragma unroll
    for (int k0 = 0; k0 < 8; ++k0) {
      bf16x8 a[2], b[4];
#pragma unroll
      for (int mti = 0; mti < 2; ++mti) {
        int row = wr * 32 + mti * 16 + lr;
        a[mti] = *(const bf16x8*)((const char*)ha + row * 512 + ((k0 * 64 + hi * 16) ^ ((row & 7) << 4)));
      }
#pragma unroll
      for (int nt = 0; nt < 4; ++nt) {
        b[nt] = *(const bf16x8*)(wyt + (size_t)(dbase + nt * 16 + lr) * 256 + k0 * 32 + hi * 8);
#pragma unroll
        for (int mti = 0; mti < 2; ++mti)
          acc[mti][nt] = __builtin_amdgcn_mfma_f32_16x16x32_bf16(a[mti], b[nt], acc[mti][nt], 0, 0, 0);
      }
    }
#pragma unroll
    for (int mti = 0; mti < 2; ++mti)
#pragma unroll
      for (int nt = 0; nt < 4; ++nt) {
        int d = dbase + nt * 16 + lr;
        float bv = by[d];
#pragma unroll
        for (int r = 0; r < 4; ++r) {
          int trow = t0 + wr * 32 + mti * 16 + hi * 4 + r;
          y[((size_t)bb * TT + trow) * DD + d] = acc[mti][nt][r] + bv;
        }
      }
  }
}

// ---------------- launch ----------------
extern "C" void kernel_launch(void* const* d_in, const int* in_sizes, int n_in,
                              void* d_out, int out_size, void* d_ws, size_t ws_size,
                              hipStream_t stream) {
  const float* x   = (const float*)d_in[0];
  const float* wih = (const float*)d_in[1];
  const float* bih = (const float*)d_in[2];
  const float* whh = (const float*)d_in[3];
  const float* h0  = (const float*)d_in[4];
  const float* c0  = (const float*)d_in[5];
  const float* wy  = (const float*)d_in[6];
  const float* by  = (const float*)d_in[7];
  float* out = (float*)d_out;
  char* ws = (char*)d_ws;

  size_t off = 0;
  unsigned short* xw = (unsigned short*)(ws + off);
  off += (size_t)(TT + 2) * BBATCH * G4 * 2;   // 512MB + 2-row prefetch slack
  unsigned short* wbf = (unsigned short*)(ws + off); off += (size_t)G4 * DD * 2;
  unsigned short* wyt = (unsigned short*)(ws + off); off += (size_t)HH * DD * 2;
  signed char* wq = (signed char*)(ws + off); off += (size_t)G4 * HH;
  float* dsc = (float*)(ws + off); off += G4 * 4;
  float* hh0 = (float*)(ws + off); off += G4 * 4;

  hipLaunchKernelGGL(prep_wih, dim3(1024), dim3(64), 0, stream, wih, wbf);
  hipLaunchKernelGGL(prep_wyt, dim3(256), dim3(256), 0, stream, wy, wyt);
  hipLaunchKernelGGL(prep_whh, dim3(1024), dim3(64), 0, stream, whh, h0, wq, dsc, hh0);
  hipLaunchKernelGGL(xw_gemm, dim3(4096), dim3(256), 0, stream, x, wbf, bih, xw);
  hipLaunchKernelGGL(fix_xw0, dim3(1024), dim3(256), 0, stream, xw, hh0);
  hipLaunchKernelGGL(lstm_scan, dim3(64), dim3(1024), 0, stream, xw, wq, dsc, c0, out);
  hipLaunchKernelGGL(y_gemm, dim3(4096), dim3(256), 0, stream, xw, wyt, by, out);
}

// Round 6
// 1374.191 us; speedup vs baseline: 3.6934x; 1.0864x over previous
//
#include <hip/hip_runtime.h>
#include <hip/hip_bf16.h>
#include <stdint.h>

#define TT 1024
#define BBATCH 256
#define DD 256
#define HH 256
#define G4 1024   // 4*H

typedef float f32x4 __attribute__((ext_vector_type(4)));
typedef short bf16x8 __attribute__((ext_vector_type(8)));
typedef int   i32x4  __attribute__((ext_vector_type(4)));
typedef unsigned long long u64;

__device__ __forceinline__ float bf2f(unsigned int u) {
  union { unsigned int i; float f; } v; v.i = u << 16; return v.f;
}
__device__ __forceinline__ unsigned short f2bf(float f) {
  union { float f; unsigned int i; } v; v.f = f;
  unsigned int r = v.i + 0x7FFFu + ((v.i >> 16) & 1u);
  return (unsigned short)(r >> 16);
}

// ---------------- prep kernels ----------------

// W_ih fp32 [1024 g][256 k] -> bf16 packed LDS-linear for xw_gemm's B staging.
// g = sec*256+n, n = nt8*32 + wc*16 + lr; k: ks=k>>6, kk=(k>>5)&1, hi=(k>>3)&3, j=k&7.
// chunk (nt8*4+ks) of 16KB; within: slot16 = ((wc*4+sec)*2+kk)*64 + (lr|hi<<4), byte slot16*16 + j*2.
__global__ void prep_wih(const float* __restrict__ wih, unsigned short* __restrict__ out) {
  int g = blockIdx.x;          // 0..1023
  int lane = threadIdx.x;      // 0..63
  int sec = g >> 8, n = g & 255;
  int nt8 = n >> 5, wc = (n >> 4) & 1, lr = n & 15;
  int k0 = lane * 4;
  int ks = k0 >> 6, kk = (k0 >> 5) & 1, hi = (k0 >> 3) & 3, j = k0 & 7;
  size_t us = (size_t)(nt8 * 4 + ks) * 8192
            + (size_t)((((wc * 4 + sec) * 2 + kk) * 64) + (lr | (hi << 4))) * 8 + j;
#pragma unroll
  for (int j2 = 0; j2 < 4; ++j2) out[us + j2] = f2bf(wih[g * 256 + k0 + j2]);
}

__global__ void prep_wyt(const float* __restrict__ wy, unsigned short* __restrict__ wyt) {
  int k = blockIdx.x;
  int d = threadIdx.x;
  wyt[d * 256 + k] = f2bf(wy[k * 256 + d]);
}

// W_hh fp32 [1024 g][256 k] -> per-row-scaled int8 packed in MFMA B-frag order for the
// 16-wave scan: g = sec*256 + n, n = w*16 + cl. Frag slot [((w*4+sec)*4+kt)*64 + lane].
__global__ void prep_whh(const float* __restrict__ whh, const float* __restrict__ h0,
                         signed char* __restrict__ wq, float* __restrict__ dsc,
                         float* __restrict__ hh0) {
  int g = blockIdx.x;
  int lane = threadIdx.x;
  float v[4];
  float mx = 0.f, acc = 0.f;
#pragma unroll
  for (int j = 0; j < 4; ++j) {
    v[j] = whh[g * 256 + lane * 4 + j];
    mx = fmaxf(mx, fabsf(v[j]));
    acc += v[j] * h0[lane * 4 + j];
  }
#pragma unroll
  for (int off = 32; off; off >>= 1) {
    mx  = fmaxf(mx, __shfl_xor(mx, off));
    acc = acc + __shfl_xor(acc, off);
  }
  mx = fmaxf(mx, 1e-12f);
  if (lane == 0) { dsc[g] = mx / (127.f * 127.f); hh0[g] = acc; }
  int sec = g >> 8, w = (g >> 4) & 15, cl = g & 15;
  float inv = 127.f / mx;
  int k0 = lane * 4;
  int kt = k0 >> 6, hi = (k0 >> 4) & 3, jj = k0 & 15;
  int base = (((w * 4 + sec) * 4 + kt) * 64 + (cl | (hi << 4))) * 16 + jj;
#pragma unroll
  for (int j = 0; j < 4; ++j) {
    int q = (int)rintf(v[j] * inv);
    q = q > 127 ? 127 : (q < -127 ? -127 : q);
    wq[base + j] = (signed char)q;
  }
}

// ---------------- phase 1: xw = x @ W_ih^T + b_ih (gate-packed bf16), m97-style 128x128 tile ----
// grid 16384 (N-tile fast), block 256 (4 waves). K=256 in 4 dbuf slices of 64.
// LDS 64KB: A[2]16KB (128 rows x 128B, XOR-swz) + B[2]16KB (frag-linear).
// hh0 folded in at trow==0 (replaces fix_xw0).
__global__ __launch_bounds__(256, 2) void xw_gemm(const float* __restrict__ x,
                                                  const unsigned short* __restrict__ wb,
                                                  const float* __restrict__ bih,
                                                  const float* __restrict__ hh0,
                                                  unsigned short* __restrict__ xw) {
  __shared__ __align__(16) char lds[65536];
  int tid = threadIdx.x;
  int bid = blockIdx.x;
  int nt8 = bid & 7;
  int mt = bid >> 3;
  int bb = mt >> 3;
  int t0 = (mt & 7) * 128;
  int lane = tid & 63, wv = tid >> 6;
  int wr = wv >> 1, wc = wv & 1;
  int lr = lane & 15, hi = lane >> 4;
  int sr = tid >> 4, sc = tid & 15;   // staging row-sub / col

  const float* xbase = x + ((size_t)bb * TT + t0) * DD;
  const unsigned short* wbase = wb + (size_t)nt8 * 4 * 8192;

  float4 rA[8];
  int4 rB[4];

#define LOADA(ks) { _Pragma("unroll") for (int i = 0; i < 8; ++i) \
    rA[i] = *(const float4*)(xbase + (size_t)(i * 16 + sr) * DD + (ks) * 64 + sc * 4); }
#define WRITEA(p) { _Pragma("unroll") for (int i = 0; i < 8; ++i) { \
    int row = i * 16 + sr; \
    u64 pk = (u64)f2bf(rA[i].x) | ((u64)f2bf(rA[i].y) << 16) \
           | ((u64)f2bf(rA[i].z) << 32) | ((u64)f2bf(rA[i].w) << 48); \
    *(u64*)(lds + (p) * 16384 + row * 128 + ((sc * 8) ^ ((row & 7) << 4))) = pk; } }
#define LOADB(ks) { _Pragma("unroll") for (int i = 0; i < 4; ++i) \
    rB[i] = *(const int4*)((const char*)wbase + (ks) * 16384 + i * 4096 + tid * 16); }
#define WRITEB(p) { _Pragma("unroll") for (int i = 0; i < 4; ++i) \
    *(int4*)(lds + 32768 + (p) * 16384 + i * 4096 + tid * 16) = rB[i]; }

  f32x4 acc[4][4];   // [mti][sec]
#pragma unroll
  for (int m = 0; m < 4; ++m)
#pragma unroll
    for (int s = 0; s < 4; ++s) acc[m][s] = (f32x4){0.f, 0.f, 0.f, 0.f};

  LOADA(0) LOADB(0)
  WRITEA(0) WRITEB(0)
  __syncthreads();

#pragma unroll 1
  for (int ks = 0; ks < 4; ++ks) {
    int p = ks & 1;
    if (ks < 3) { LOADA(ks + 1) LOADB(ks + 1) }
#pragma unroll
    for (int kk = 0; kk < 2; ++kk) {
      bf16x8 a[4], b[4];
#pragma unroll
      for (int m = 0; m < 4; ++m)
        a[m] = *(const bf16x8*)(lds + p * 16384 + (wr * 64 + m * 16 + lr) * 128
                                + ((kk * 64 + hi * 16) ^ ((lr & 7) << 4)));
#pragma unroll
      for (int s = 0; s < 4; ++s)
        b[s] = *(const bf16x8*)(lds + 32768 + p * 16384
                                + ((((wc * 4 + s) * 2 + kk) * 64 + lane) * 16));
#pragma unroll
      for (int m = 0; m < 4; ++m)
#pragma unroll
        for (int s = 0; s < 4; ++s)
          acc[m][s] = __builtin_amdgcn_mfma_f32_16x16x32_bf16(a[m], b[s], acc[m][s], 0, 0, 0);
    }
    if (ks < 3) { WRITEA(p ^ 1) WRITEB(p ^ 1) }
    __syncthreads();
  }
#undef LOADA
#undef WRITEA
#undef LOADB
#undef WRITEB

  // epilogue: pack 4 secs -> u64, add bias (+hh0 at t==0), contiguous 8B stores
  int n = nt8 * 32 + wc * 16 + lr;
  float bias[4], h0a[4];
#pragma unroll
  for (int s = 0; s < 4; ++s) { bias[s] = bih[s * 256 + n]; h0a[s] = hh0[s * 256 + n]; }
#pragma unroll
  for (int m = 0; m < 4; ++m) {
#pragma unroll
    for (int r = 0; r < 4; ++r) {
      int trow = t0 + wr * 64 + m * 16 + hi * 4 + r;
      float e[4];
#pragma unroll
      for (int s = 0; s < 4; ++s)
        e[s] = acc[m][s][r] + bias[s] + (trow == 0 ? h0a[s] : 0.f);
      u64 pk = (u64)f2bf(e[0]) | ((u64)f2bf(e[1]) << 16)
             | ((u64)f2bf(e[2]) << 32) | ((u64)f2bf(e[3]) << 48);
      *(u64*)(xw + ((size_t)trow * BBATCH + bb) * G4 + (size_t)n * 4) = pk;
    }
  }
}

// ---------------- phase 2: the scan ----------------
// 64 blocks x 1024 threads (16 waves, 4/SIMD). Block owns 4 batches (A/C rows 4b).
// Wave wv owns n-range wv*16..+16, all 4 gates (nt=sec). Per lane per step:
// 16 MFMA, 1 gate-set, 1 u64 xw load (prefetched 2 ahead), 1 hq byte, 1 hs bf16.
__global__ __launch_bounds__(1024, 1) void lstm_scan(unsigned short* xw,
                                                     const signed char* __restrict__ wq,
                                                     const float* __restrict__ dsc,
                                                     const float* __restrict__ c0,
                                                     float* __restrict__ out) {
  __shared__ __align__(16) signed char hq[2][4][64][16];  // 8KB, double-buffered int8 h A-frags
  int tid = threadIdx.x;
  int lane = tid & 63, wv = tid >> 6;
  int lr = lane & 15, q = lane >> 4;
  int b0 = blockIdx.x * 4;
  signed char* hqb = (signed char*)hq;
  int nn = wv * 16 + lr;

  // resident W_hh int8 B-frags: 16 i32x4 = 64 VGPRs
  i32x4 wf[4][4];
  {
    const i32x4* wp = (const i32x4*)wq;
#pragma unroll
    for (int sec = 0; sec < 4; ++sec)
#pragma unroll
      for (int kt = 0; kt < 4; ++kt) wf[sec][kt] = wp[((wv * 4 + sec) * 4 + kt) * 64 + lane];
  }
  float dr[4];
#pragma unroll
  for (int sec = 0; sec < 4; ++sec) dr[sec] = dsc[sec * 256 + nn];
  float cr = c0[nn], lh = 0.f;

  // zero both hq buffers (8KB = 1024 threads * 8B)
  *(u64*)(hqb + tid * 8) = 0ull;

  // per-lane pointers
  unsigned short* ldb = xw + (size_t)(b0 + q) * G4 + (size_t)nn * 4;
  unsigned short* stb = xw + (size_t)(b0 + q) * G4 + nn;
  u64 xq[4];
#pragma unroll
  for (int s = 0; s < 2; ++s) {
    xq[s] = *(const u64*)ldb;
    ldb += (size_t)BBATCH * G4;
  }

  const int hqr = lane * 16;
  // producer write: kt = wv>>2, hi = wv&3, row = 4q, byte j = lr
  const int hqw = (wv >> 2) * 1024 + (wv & 3) * 256 + q * 64 + lr;
  const i32x4 zero4 = {0, 0, 0, 0};

  __syncthreads();  // hq zero visible

#define STEP(XC, XL, RB) { \
    XL = *(const u64*)ldb; \
    ldb += (size_t)BBATCH * G4; \
    i32x4 acc[4]; \
    __builtin_amdgcn_s_setprio(1); \
    _Pragma("unroll") \
    for (int kt = 0; kt < 4; ++kt) { \
      i32x4 af = *(const i32x4*)(hqb + (RB) + hqr + kt * 1024); \
      _Pragma("unroll") \
      for (int sec = 0; sec < 4; ++sec) \
        acc[sec] = __builtin_amdgcn_mfma_i32_16x16x64_i8(af, wf[sec][kt], kt == 0 ? zero4 : acc[sec], 0, 0, 0); \
    } \
    __builtin_amdgcn_s_setprio(0); \
    { \
      u64 v = XC; \
      float gi = fmaf(dr[0], (float)acc[0][0], bf2f((unsigned int)(v & 0xffffu))); \
      float gf = fmaf(dr[1], (float)acc[1][0], bf2f((unsigned int)((v >> 16) & 0xffffu))); \
      float gj = fmaf(dr[2], (float)acc[2][0], bf2f((unsigned int)((v >> 32) & 0xffffu))); \
      float go = fmaf(dr[3], (float)acc[3][0], bf2f((unsigned int)(v >> 48))); \
      float iv = __builtin_amdgcn_rcpf(1.f + __expf(-gi)); \
      float fv = __builtin_amdgcn_rcpf(1.f + __expf(-gf)); \
      float ov = __builtin_amdgcn_rcpf(1.f + __expf(-go)); \
      float jv = fmaf(-2.f, __builtin_amdgcn_rcpf(1.f + __expf(2.f * gj)), 1.f); \
      float cn = fmaf(fv, cr, iv * jv); \
      cr = cn; \
      float th = fmaf(-2.f, __builtin_amdgcn_rcpf(1.f + __expf(2.f * cn)), 1.f); \
      float hn = ov * th; \
      lh = hn; \
      hqb[((RB) ^ 4096) + hqw] = (signed char)(int)rintf(hn * 127.f); \
      stb[0] = f2bf(hn); \
    } \
    stb += (size_t)BBATCH * G4; \
    asm volatile("s_waitcnt lgkmcnt(0)" ::: "memory"); \
    __builtin_amdgcn_s_barrier(); \
  }

#pragma unroll 1
  for (int t = 0; t < TT; t += 4) {
    STEP(xq[0], xq[2], 0)
    STEP(xq[1], xq[3], 4096)
    STEP(xq[2], xq[0], 0)
    STEP(xq[3], xq[1], 4096)
  }
#undef STEP

  const size_t youts = (size_t)BBATCH * TT * DD;
  out[youts + (size_t)(b0 + q) * HH + nn] = lh;
  out[youts + (size_t)BBATCH * HH + (size_t)(b0 + q) * HH + nn] = cr;
}

// ---------------- phase 3: y = hs @ W_y + b_y ----------------
__global__ __launch_bounds__(256, 4) void y_gemm(const unsigned short* __restrict__ hsx,
                                                 const unsigned short* __restrict__ wyt,
                                                 const float* __restrict__ by,
                                                 float* __restrict__ y) {
  __shared__ __align__(16) unsigned short ha[64 * 256];  // 32KB
  int tid = threadIdx.x;
  int mt = blockIdx.x;
  int bb = mt >> 4;
  int t0 = (mt & 15) * 64;
  {
    int row = tid >> 2, q = tid & 3;
    const unsigned short* src = hsx + (size_t)(t0 + row) * (size_t)(BBATCH * 1024) + (size_t)bb * 1024;
#pragma unroll
    for (int i = 0; i < 8; ++i) {
      int u = q + i * 4;
      int4 vv = *(const int4*)(src + u * 8);
      *(int4*)((char*)ha + row * 512 + ((u * 16) ^ ((row & 7) << 4))) = vv;
    }
  }
  __syncthreads();
  int lane = tid & 63, wv = tid >> 6;
  int wr = wv >> 1, wc = wv & 1;
  int lr = lane & 15, hi = lane >> 4;
#pragma unroll 1
  for (int dblk = 0; dblk < 2; ++dblk) {
    f32x4 acc[2][4];
#pragma unroll
    for (int a = 0; a < 2; ++a)
#pragma unroll
      for (int b = 0; b < 4; ++b) acc[a][b] = (f32x4){0.f, 0.f, 0.f, 0.f};
    int dbase = dblk * 128 + wc * 64;
#pragma unroll
    for (int k0 = 0; k0 < 8; ++k0) {
      bf16x8 a[2], b[4];
#pragma unroll
      for (int mti = 0; mti < 2; ++mti) {
        int row = wr * 32 + mti * 16 + lr;
        a[mti] = *(const bf16x8*)((const char*)ha + row * 512 + ((k0 * 64 + hi * 16) ^ ((row & 7) << 4)));
      }
#pragma unroll
      for (int nt = 0; nt < 4; ++nt) {
        b[nt] = *(const bf16x8*)(wyt + (size_t)(dbase + nt * 16 + lr) * 256 + k0 * 32 + hi * 8);
#pragma unroll
        for (int mti = 0; mti < 2; ++mti)
          acc[mti][nt] = __builtin_amdgcn_mfma_f32_16x16x32_bf16(a[mti], b[nt], acc[mti][nt], 0, 0, 0);
      }
    }
#pragma unroll
    for (int mti = 0; mti < 2; ++mti)
#pragma unroll
      for (int nt = 0; nt < 4; ++nt) {
        int d = dbase + nt * 16 + lr;
        float bv = by[d];
#pragma unroll
        for (int r = 0; r < 4; ++r) {
          int trow = t0 + wr * 32 + mti * 16 + hi * 4 + r;
          y[((size_t)bb * TT + trow) * DD + d] = acc[mti][nt][r] + bv;
        }
      }
  }
}

// ---------------- launch ----------------
extern "C" void kernel_launch(void* const* d_in, const int* in_sizes, int n_in,
                              void* d_out, int out_size, void* d_ws, size_t ws_size,
                              hipStream_t stream) {
  const float* x   = (const float*)d_in[0];
  const float* wih = (const float*)d_in[1];
  const float* bih = (const float*)d_in[2];
  const float* whh = (const float*)d_in[3];
  const float* h0  = (const float*)d_in[4];
  const float* c0  = (const float*)d_in[5];
  const float* wy  = (const float*)d_in[6];
  const float* by  = (const float*)d_in[7];
  float* out = (float*)d_out;
  char* ws = (char*)d_ws;

  size_t off = 0;
  unsigned short* xw = (unsigned short*)(ws + off);
  off += (size_t)(TT + 2) * BBATCH * G4 * 2;   // 512MB + 2-row prefetch slack
  unsigned short* wbf = (unsigned short*)(ws + off); off += (size_t)G4 * DD * 2;
  unsigned short* wyt = (unsigned short*)(ws + off); off += (size_t)HH * DD * 2;
  signed char* wq = (signed char*)(ws + off); off += (size_t)G4 * HH;
  float* dsc = (float*)(ws + off); off += G4 * 4;
  float* hh0 = (float*)(ws + off); off += G4 * 4;

  hipLaunchKernelGGL(prep_wih, dim3(1024), dim3(64), 0, stream, wih, wbf);
  hipLaunchKernelGGL(prep_wyt, dim3(256), dim3(256), 0, stream, wy, wyt);
  hipLaunchKernelGGL(prep_whh, dim3(1024), dim3(64), 0, stream, whh, h0, wq, dsc, hh0);
  hipLaunchKernelGGL(xw_gemm, dim3(16384), dim3(256), 0, stream, x, wbf, bih, hh0, xw);
  hipLaunchKernelGGL(lstm_scan, dim3(64), dim3(1024), 0, stream, xw, wq, dsc, c0, out);
  hipLaunchKernelGGL(y_gemm, dim3(4096), dim3(256), 0, stream, xw, wyt, by, out);
}

// Round 7
// 1346.076 us; speedup vs baseline: 3.7705x; 1.0209x over previous
//
#include <hip/hip_runtime.h>
#include <hip/hip_bf16.h>
#include <stdint.h>

#define TT 1024
#define BBATCH 256
#define DD 256
#define HH 256
#define G4 1024   // 4*H

typedef float f32x4 __attribute__((ext_vector_type(4)));
typedef short bf16x8 __attribute__((ext_vector_type(8)));
typedef int   i32x4  __attribute__((ext_vector_type(4)));
typedef unsigned long long u64;

__device__ __forceinline__ float bf2f(unsigned int u) {
  union { unsigned int i; float f; } v; v.i = u << 16; return v.f;
}
__device__ __forceinline__ unsigned short f2bf(float f) {
  union { float f; unsigned int i; } v; v.f = f;
  unsigned int r = v.i + 0x7FFFu + ((v.i >> 16) & 1u);
  return (unsigned short)(r >> 16);
}

// ---------------- prep kernels ----------------

// W_ih fp32 [1024 g][256 k] -> bf16 packed LDS-linear for xw_gemm's B staging.
__global__ void prep_wih(const float* __restrict__ wih, unsigned short* __restrict__ out) {
  int g = blockIdx.x;          // 0..1023
  int lane = threadIdx.x;      // 0..63
  int sec = g >> 8, n = g & 255;
  int nt8 = n >> 5, wc = (n >> 4) & 1, lr = n & 15;
  int k0 = lane * 4;
  int ks = k0 >> 6, kk = (k0 >> 5) & 1, hi = (k0 >> 3) & 3, j = k0 & 7;
  size_t us = (size_t)(nt8 * 4 + ks) * 8192
            + (size_t)((((wc * 4 + sec) * 2 + kk) * 64) + (lr | (hi << 4))) * 8 + j;
#pragma unroll
  for (int j2 = 0; j2 < 4; ++j2) out[us + j2] = f2bf(wih[g * 256 + k0 + j2]);
}

__global__ void prep_wyt(const float* __restrict__ wy, unsigned short* __restrict__ wyt) {
  int k = blockIdx.x;
  int d = threadIdx.x;
  wyt[d * 256 + k] = f2bf(wy[k * 256 + d]);
}

// W_hh fp32 [1024 g][256 k] -> per-row-scaled int8 packed in MFMA B-frag order for the
// 16-wave scan: g = sec*256 + n, n = w*16 + cl. Frag slot [((w*4+sec)*4+kt)*64 + lane].
__global__ void prep_whh(const float* __restrict__ whh, const float* __restrict__ h0,
                         signed char* __restrict__ wq, float* __restrict__ dsc,
                         float* __restrict__ hh0) {
  int g = blockIdx.x;
  int lane = threadIdx.x;
  float v[4];
  float mx = 0.f, acc = 0.f;
#pragma unroll
  for (int j = 0; j < 4; ++j) {
    v[j] = whh[g * 256 + lane * 4 + j];
    mx = fmaxf(mx, fabsf(v[j]));
    acc += v[j] * h0[lane * 4 + j];
  }
#pragma unroll
  for (int off = 32; off; off >>= 1) {
    mx  = fmaxf(mx, __shfl_xor(mx, off));
    acc = acc + __shfl_xor(acc, off);
  }
  mx = fmaxf(mx, 1e-12f);
  if (lane == 0) { dsc[g] = mx / (127.f * 127.f); hh0[g] = acc; }
  int sec = g >> 8, w = (g >> 4) & 15, cl = g & 15;
  float inv = 127.f / mx;
  int k0 = lane * 4;
  int kt = k0 >> 6, hi = (k0 >> 4) & 3, jj = k0 & 15;
  int base = (((w * 4 + sec) * 4 + kt) * 64 + (cl | (hi << 4))) * 16 + jj;
#pragma unroll
  for (int j = 0; j < 4; ++j) {
    int q = (int)rintf(v[j] * inv);
    q = q > 127 ? 127 : (q < -127 ? -127 : q);
    wq[base + j] = (signed char)q;
  }
}

// ---------------- phase 1: xw = x @ W_ih^T + b_ih (gate-packed bf16), 128x128 tile ----
// grid 16384, block 256 (4 waves). XCD-aware bid remap: the 8 nt8-peers sharing one
// A-tile (same mt) land on the SAME XCD as consecutive slots -> x re-reads hit XCD L2.
__global__ __launch_bounds__(256, 2) void xw_gemm(const float* __restrict__ x,
                                                  const unsigned short* __restrict__ wb,
                                                  const float* __restrict__ bih,
                                                  const float* __restrict__ hh0,
                                                  unsigned short* __restrict__ xw) {
  __shared__ __align__(16) char lds[65536];
  int tid = threadIdx.x;
  int bid = blockIdx.x;
  // bid = xcd + 8*(nt8 + 8*m8); mt = xcd + 8*m8  (bijective; 2048 mt x 8 nt8)
  int xcd = bid & 7, sl = bid >> 3;
  int nt8 = sl & 7;
  int mt = xcd + 8 * (sl >> 3);
  int bb = mt >> 3;
  int t0 = (mt & 7) * 128;
  int lane = tid & 63, wv = tid >> 6;
  int wr = wv >> 1, wc = wv & 1;
  int lr = lane & 15, hi = lane >> 4;
  int sr = tid >> 4, sc = tid & 15;   // staging row-sub / col

  const float* xbase = x + ((size_t)bb * TT + t0) * DD;
  const unsigned short* wbase = wb + (size_t)nt8 * 4 * 8192;

  float4 rA[8];
  int4 rB[4];

#define LOADA(ks) { _Pragma("unroll") for (int i = 0; i < 8; ++i) \
    rA[i] = *(const float4*)(xbase + (size_t)(i * 16 + sr) * DD + (ks) * 64 + sc * 4); }
#define WRITEA(p) { _Pragma("unroll") for (int i = 0; i < 8; ++i) { \
    int row = i * 16 + sr; \
    u64 pk = (u64)f2bf(rA[i].x) | ((u64)f2bf(rA[i].y) << 16) \
           | ((u64)f2bf(rA[i].z) << 32) | ((u64)f2bf(rA[i].w) << 48); \
    *(u64*)(lds + (p) * 16384 + row * 128 + ((sc * 8) ^ ((row & 7) << 4))) = pk; } }
#define LOADB(ks) { _Pragma("unroll") for (int i = 0; i < 4; ++i) \
    rB[i] = *(const int4*)((const char*)wbase + (ks) * 16384 + i * 4096 + tid * 16); }
#define WRITEB(p) { _Pragma("unroll") for (int i = 0; i < 4; ++i) \
    *(int4*)(lds + 32768 + (p) * 16384 + i * 4096 + tid * 16) = rB[i]; }

  f32x4 acc[4][4];   // [mti][sec]
#pragma unroll
  for (int m = 0; m < 4; ++m)
#pragma unroll
    for (int s = 0; s < 4; ++s) acc[m][s] = (f32x4){0.f, 0.f, 0.f, 0.f};

  LOADA(0) LOADB(0)
  WRITEA(0) WRITEB(0)
  __syncthreads();

#pragma unroll 1
  for (int ks = 0; ks < 4; ++ks) {
    int p = ks & 1;
    if (ks < 3) { LOADA(ks + 1) LOADB(ks + 1) }
#pragma unroll
    for (int kk = 0; kk < 2; ++kk) {
      bf16x8 a[4], b[4];
#pragma unroll
      for (int m = 0; m < 4; ++m)
        a[m] = *(const bf16x8*)(lds + p * 16384 + (wr * 64 + m * 16 + lr) * 128
                                + ((kk * 64 + hi * 16) ^ ((lr & 7) << 4)));
#pragma unroll
      for (int s = 0; s < 4; ++s)
        b[s] = *(const bf16x8*)(lds + 32768 + p * 16384
                                + ((((wc * 4 + s) * 2 + kk) * 64 + lane) * 16));
#pragma unroll
      for (int m = 0; m < 4; ++m)
#pragma unroll
        for (int s = 0; s < 4; ++s)
          acc[m][s] = __builtin_amdgcn_mfma_f32_16x16x32_bf16(a[m], b[s], acc[m][s], 0, 0, 0);
    }
    if (ks < 3) { WRITEA(p ^ 1) WRITEB(p ^ 1) }
    __syncthreads();
  }
#undef LOADA
#undef WRITEA
#undef LOADB
#undef WRITEB

  // epilogue: pack 4 secs -> u64, add bias (+hh0 at t==0), contiguous 8B stores
  int n = nt8 * 32 + wc * 16 + lr;
  float bias[4], h0a[4];
#pragma unroll
  for (int s = 0; s < 4; ++s) { bias[s] = bih[s * 256 + n]; h0a[s] = hh0[s * 256 + n]; }
#pragma unroll
  for (int m = 0; m < 4; ++m) {
#pragma unroll
    for (int r = 0; r < 4; ++r) {
      int trow = t0 + wr * 64 + m * 16 + hi * 4 + r;
      float e[4];
#pragma unroll
      for (int s = 0; s < 4; ++s)
        e[s] = acc[m][s][r] + bias[s] + (trow == 0 ? h0a[s] : 0.f);
      u64 pk = (u64)f2bf(e[0]) | ((u64)f2bf(e[1]) << 16)
             | ((u64)f2bf(e[2]) << 32) | ((u64)f2bf(e[3]) << 48);
      *(u64*)(xw + ((size_t)trow * BBATCH + bb) * G4 + (size_t)n * 4) = pk;
    }
  }
}

// ---------------- phase 2: the scan ----------------
// 64 blocks x 1024 threads (16 waves, 4/SIMD). Block owns 4 batches (A/C rows 4b).
// Per-SIMD issue floor: 64 i8-MFMA x 20.4cyc = 1306 cyc/step; measured 1793 -> ~90% optimal.
__global__ __launch_bounds__(1024, 1) void lstm_scan(unsigned short* xw,
                                                     const signed char* __restrict__ wq,
                                                     const float* __restrict__ dsc,
                                                     const float* __restrict__ c0,
                                                     float* __restrict__ out) {
  __shared__ __align__(16) signed char hq[2][4][64][16];  // 8KB, double-buffered int8 h A-frags
  int tid = threadIdx.x;
  int lane = tid & 63, wv = tid >> 6;
  int lr = lane & 15, q = lane >> 4;
  int b0 = blockIdx.x * 4;
  signed char* hqb = (signed char*)hq;
  int nn = wv * 16 + lr;

  // resident W_hh int8 B-frags: 16 i32x4 = 64 VGPRs
  i32x4 wf[4][4];
  {
    const i32x4* wp = (const i32x4*)wq;
#pragma unroll
    for (int sec = 0; sec < 4; ++sec)
#pragma unroll
      for (int kt = 0; kt < 4; ++kt) wf[sec][kt] = wp[((wv * 4 + sec) * 4 + kt) * 64 + lane];
  }
  float dr[4];
#pragma unroll
  for (int sec = 0; sec < 4; ++sec) dr[sec] = dsc[sec * 256 + nn];
  float cr = c0[nn], lh = 0.f;

  // zero both hq buffers (8KB = 1024 threads * 8B)
  *(u64*)(hqb + tid * 8) = 0ull;

  // per-lane pointers
  unsigned short* ldb = xw + (size_t)(b0 + q) * G4 + (size_t)nn * 4;
  unsigned short* stb = xw + (size_t)(b0 + q) * G4 + nn;
  u64 xq[4];
#pragma unroll
  for (int s = 0; s < 2; ++s) {
    xq[s] = *(const u64*)ldb;
    ldb += (size_t)BBATCH * G4;
  }

  const int hqr = lane * 16;
  // producer write: kt = wv>>2, hi = wv&3, row = 4q, byte j = lr
  const int hqw = (wv >> 2) * 1024 + (wv & 3) * 256 + q * 64 + lr;
  const i32x4 zero4 = {0, 0, 0, 0};

  __syncthreads();  // hq zero visible

#define STEP(XC, XL, RB) { \
    XL = *(const u64*)ldb; \
    ldb += (size_t)BBATCH * G4; \
    i32x4 acc[4]; \
    __builtin_amdgcn_s_setprio(1); \
    _Pragma("unroll") \
    for (int kt = 0; kt < 4; ++kt) { \
      i32x4 af = *(const i32x4*)(hqb + (RB) + hqr + kt * 1024); \
      _Pragma("unroll") \
      for (int sec = 0; sec < 4; ++sec) \
        acc[sec] = __builtin_amdgcn_mfma_i32_16x16x64_i8(af, wf[sec][kt], kt == 0 ? zero4 : acc[sec], 0, 0, 0); \
    } \
    __builtin_amdgcn_s_setprio(0); \
    { \
      u64 v = XC; \
      float gi = fmaf(dr[0], (float)acc[0][0], bf2f((unsigned int)(v & 0xffffu))); \
      float gf = fmaf(dr[1], (float)acc[1][0], bf2f((unsigned int)((v >> 16) & 0xffffu))); \
      float gj = fmaf(dr[2], (float)acc[2][0], bf2f((unsigned int)((v >> 32) & 0xffffu))); \
      float go = fmaf(dr[3], (float)acc[3][0], bf2f((unsigned int)(v >> 48))); \
      float iv = __builtin_amdgcn_rcpf(1.f + __expf(-gi)); \
      float fv = __builtin_amdgcn_rcpf(1.f + __expf(-gf)); \
      float ov = __builtin_amdgcn_rcpf(1.f + __expf(-go)); \
      float jv = fmaf(-2.f, __builtin_amdgcn_rcpf(1.f + __expf(2.f * gj)), 1.f); \
      float cn = fmaf(fv, cr, iv * jv); \
      cr = cn; \
      float th = fmaf(-2.f, __builtin_amdgcn_rcpf(1.f + __expf(2.f * cn)), 1.f); \
      float hn = ov * th; \
      lh = hn; \
      hqb[((RB) ^ 4096) + hqw] = (signed char)(int)rintf(hn * 127.f); \
      stb[0] = f2bf(hn); \
    } \
    stb += (size_t)BBATCH * G4; \
    asm volatile("s_waitcnt lgkmcnt(0)" ::: "memory"); \
    __builtin_amdgcn_s_barrier(); \
  }

#pragma unroll 1
  for (int t = 0; t < TT; t += 4) {
    STEP(xq[0], xq[2], 0)
    STEP(xq[1], xq[3], 4096)
    STEP(xq[2], xq[0], 0)
    STEP(xq[3], xq[1], 4096)
  }
#undef STEP

  const size_t youts = (size_t)BBATCH * TT * DD;
  out[youts + (size_t)(b0 + q) * HH + nn] = lh;
  out[youts + (size_t)BBATCH * HH + (size_t)(b0 + q) * HH + nn] = cr;
}

// ---------------- phase 3: y = hs @ W_y + b_y ----------------
__global__ __launch_bounds__(256, 4) void y_gemm(const unsigned short* __restrict__ hsx,
                                                 const unsigned short* __restrict__ wyt,
                                                 const float* __restrict__ by,
                                                 float* __restrict__ y) {
  __shared__ __align__(16) unsigned short ha[64 * 256];  // 32KB
  int tid = threadIdx.x;
  int mt = blockIdx.x;
  int bb = mt >> 4;
  int t0 = (mt & 15) * 64;
  {
    int row = tid >> 2, q = tid & 3;
    const unsigned short* src = hsx + (size_t)(t0 + row) * (size_t)(BBATCH * 1024) + (size_t)bb * 1024;
#pragma unroll
    for (int i = 0; i < 8; ++i) {
      int u = q + i * 4;
      int4 vv = *(const int4*)(src + u * 8);
      *(int4*)((char*)ha + row * 512 + ((u * 16) ^ ((row & 7) << 4))) = vv;
    }
  }
  __syncthreads();
  int lane = tid & 63, wv = tid >> 6;
  int wr = wv >> 1, wc = wv & 1;
  int lr = lane & 15, hi = lane >> 4;
#pragma unroll 1
  for (int dblk = 0; dblk < 2; ++dblk) {
    f32x4 acc[2][4];
#pragma unroll
    for (int a = 0; a < 2; ++a)
#pragma unroll
      for (int b = 0; b < 4; ++b) acc[a][b] = (f32x4){0.f, 0.f, 0.f, 0.f};
    int dbase = dblk * 128 + wc * 64;
#pragma unroll
    for (int k0 = 0; k0 < 8; ++k0) {
      bf16x8 a[2], b[4];
#pragma unroll
      for (int mti = 0; mti < 2; ++mti) {
        int row = wr * 32 + mti * 16 + lr;
        a[mti] = *(const bf16x8*)((const char*)ha + row * 512 + ((k0 * 64 + hi * 16) ^ ((row & 7) << 4)));
      }
#pragma unroll
      for (int nt = 0; nt < 4; ++nt) {
        b[nt] = *(const bf16x8*)(wyt + (size_t)(dbase + nt * 16 + lr) * 256 + k0 * 32 + hi * 8);
#pragma unroll
        for (int mti = 0; mti < 2; ++mti)
          acc[mti][nt] = __builtin_amdgcn_mfma_f32_16x16x32_bf16(a[mti], b[nt], acc[mti][nt], 0, 0, 0);
      }
    }
#pragma unroll
    for (int mti = 0; mti < 2; ++mti)
#pragma unroll
      for (int nt = 0; nt < 4; ++nt) {
        int d = dbase + nt * 16 + lr;
        float bv = by[d];
#pragma unroll
        for (int r = 0; r < 4; ++r) {
          int trow = t0 + wr * 32 + mti * 16 + hi * 4 + r;
          y[((size_t)bb * TT + trow) * DD + d] = acc[mti][nt][r] + bv;
        }
      }
  }
}

// ---------------- launch ----------------
extern "C" void kernel_launch(void* const* d_in, const int* in_sizes, int n_in,
                              void* d_out, int out_size, void* d_ws, size_t ws_size,
                              hipStream_t stream) {
  const float* x   = (const float*)d_in[0];
  const float* wih = (const float*)d_in[1];
  const float* bih = (const float*)d_in[2];
  const float* whh = (const float*)d_in[3];
  const float* h0  = (const float*)d_in[4];
  const float* c0  = (const float*)d_in[5];
  const float* wy  = (const float*)d_in[6];
  const float* by  = (const float*)d_in[7];
  float* out = (float*)d_out;
  char* ws = (char*)d_ws;

  size_t off = 0;
  unsigned short* xw = (unsigned short*)(ws + off);
  off += (size_t)(TT + 2) * BBATCH * G4 * 2;   // 512MB + 2-row prefetch slack
  unsigned short* wbf = (unsigned short*)(ws + off); off += (size_t)G4 * DD * 2;
  unsigned short* wyt = (unsigned short*)(ws + off); off += (size_t)HH * DD * 2;
  signed char* wq = (signed char*)(ws + off); off += (size_t)G4 * HH;
  float* dsc = (float*)(ws + off); off += G4 * 4;
  float* hh0 = (float*)(ws + off); off += G4 * 4;

  hipLaunchKernelGGL(prep_wih, dim3(1024), dim3(64), 0, stream, wih, wbf);
  hipLaunchKernelGGL(prep_wyt, dim3(256), dim3(256), 0, stream, wy, wyt);
  hipLaunchKernelGGL(prep_whh, dim3(1024), dim3(64), 0, stream, whh, h0, wq, dsc, hh0);
  hipLaunchKernelGGL(xw_gemm, dim3(16384), dim3(256), 0, stream, x, wbf, bih, hh0, xw);
  hipLaunchKernelGGL(lstm_scan, dim3(64), dim3(1024), 0, stream, xw, wq, dsc, c0, out);
  hipLaunchKernelGGL(y_gemm, dim3(4096), dim3(256), 0, stream, xw, wyt, by, out);
}